// Round 10
// baseline (768.744 us; speedup 1.0000x reference)
//
#include <hip/hip_runtime.h>
#include <math.h>

// ---------------------------------------------------------------------------
// SiReN loss on MI355X — round 10: k_node de-LDS-bottlenecking.
// k-chunked float4 (ds_read_b128) operand reads, weights streamed from
// global/L1 (k-contiguous), no weight LDS buffer. TS=68 (4-aligned rows,
// conflict-free b128). LDS 51.2 -> 34.8 KB => 4 blocks/CU.
// ---------------------------------------------------------------------------

// count + per-edge rank within its dst bucket (arrival order)
__global__ void k_count(const int* __restrict__ dst, int* __restrict__ deg,
                        int* __restrict__ rank, int NE) {
  int e = blockIdx.x * blockDim.x + threadIdx.x;
  if (e < NE) rank[e] = atomicAdd(&deg[dst[e]], 1);
}

__global__ void k_scan1(const int* __restrict__ deg, int* __restrict__ bsum, int NN) {
  __shared__ int sm[256];
  int t = threadIdx.x;
  int i = blockIdx.x * 256 + t;
  sm[t] = (i < NN) ? deg[i] : 0;
  __syncthreads();
  for (int s = 128; s > 0; s >>= 1) {
    if (t < s) sm[t] += sm[t + s];
    __syncthreads();
  }
  if (t == 0) bsum[blockIdx.x] = sm[0];
}

__global__ void k_scan2(int* __restrict__ bsum, int nb) {
  __shared__ int sm[1024];
  int t = threadIdx.x;
  int v = (t < nb) ? bsum[t] : 0;
  sm[t] = v;
  __syncthreads();
  for (int off = 1; off < 1024; off <<= 1) {
    int add = (t >= off) ? sm[t - off] : 0;
    __syncthreads();
    sm[t] += add;
    __syncthreads();
  }
  if (t < nb) bsum[t] = sm[t] - v;  // exclusive
}

__global__ void k_scan3(const int* __restrict__ deg, const int* __restrict__ bsum,
                        int* __restrict__ rowptr, int NN) {
  __shared__ int sm[256];
  int t = threadIdx.x;
  int i = blockIdx.x * 256 + t;
  int v = (i < NN) ? deg[i] : 0;
  sm[t] = v;
  __syncthreads();
  for (int off = 1; off < 256; off <<= 1) {
    int add = (t >= off) ? sm[t - off] : 0;
    __syncthreads();
    sm[t] += add;
    __syncthreads();
  }
  int incl = sm[t] + bsum[blockIdx.x];
  if (i < NN) rowptr[i] = incl - v;
  if (i == NN - 1) rowptr[NN] = incl;
}

__global__ void k_dinv(const int* __restrict__ deg, float* __restrict__ dinv, int NN) {
  int i = blockIdx.x * blockDim.x + threadIdx.x;
  if (i < NN) {
    int d = deg[i];
    dinv[i] = (d > 0) ? rsqrtf((float)d) : 0.f;
  }
}

// atomic-free scatter: pos = rowptr[dst] + rank
__global__ void k_scatter(const int* __restrict__ src, const int* __restrict__ dst,
                          const int* __restrict__ rowptr, const int* __restrict__ rank,
                          int* __restrict__ csrc, int NE) {
  int e = blockIdx.x * blockDim.x + threadIdx.x;
  if (e >= NE) return;
  int d = dst[e];
  csrc[rowptr[d] + rank[e]] = src[e];
}

// 16-lane sub-group per node, lane = 4 dims (float4); 4 nodes per wave
__global__ __launch_bounds__(256) void k_gather(const float* __restrict__ x,
                                                const int* __restrict__ rowptr,
                                                const int* __restrict__ csrc,
                                                const float* __restrict__ dinv,
                                                float* __restrict__ out, int NN) {
  int gid = blockIdx.x * blockDim.x + threadIdx.x;
  int node = gid >> 4;
  if (node >= NN) return;
  int sl = gid & 15;
  int beg = rowptr[node], end = rowptr[node + 1];
  float dn = dinv[node];
  float ax = 0.f, ay = 0.f, az = 0.f, aw = 0.f;
  int i = beg;
  for (; i + 1 < end; i += 2) {
    int s0 = csrc[i], s1 = csrc[i + 1];
    float n0 = dinv[s0], n1 = dinv[s1];
    float4 x0 = *(const float4*)&x[(size_t)s0 * 64 + sl * 4];
    float4 x1 = *(const float4*)&x[(size_t)s1 * 64 + sl * 4];
    ax += n0 * x0.x; ay += n0 * x0.y; az += n0 * x0.z; aw += n0 * x0.w;
    ax += n1 * x1.x; ay += n1 * x1.y; az += n1 * x1.z; aw += n1 * x1.w;
  }
  if (i < end) {
    int s0 = csrc[i];
    float n0 = dinv[s0];
    float4 x0 = *(const float4*)&x[(size_t)s0 * 64 + sl * 4];
    ax += n0 * x0.x; ay += n0 * x0.y; az += n0 * x0.z; aw += n0 * x0.w;
  }
  float4 r; r.x = ax * dn; r.y = ay * dn; r.z = az * dn; r.w = aw * dn;
  *(float4*)&out[(size_t)node * 64 + sl * 4] = r;
}

// ---------------------------------------------------------------------------
// k_node v5: 64-node tile per block; 4x4 register tiling; k-chunked float4
// LDS reads (b128); weights streamed from global (L1-resident, k-contiguous).
// Phases: stage TA=E2 | GEMM1->TB=H | GEMM2->acc | TA=ZN, TB=ZP | attn | out.
// ---------------------------------------------------------------------------
#define TS 68

__device__ inline float fast_tanh(float x) {
  float t = __expf(fminf(fmaxf(2.f * x, -30.f), 30.f));
  return (t - 1.f) / (t + 1.f);
}

__device__ inline void dot4(float acc[4][4], const float4 xv[4], const float4 wv[4]) {
#pragma unroll
  for (int a = 0; a < 4; ++a)
#pragma unroll
    for (int b = 0; b < 4; ++b) {
      acc[a][b] += xv[a].x * wv[b].x;
      acc[a][b] += xv[a].y * wv[b].y;
      acc[a][b] += xv[a].z * wv[b].z;
      acc[a][b] += xv[a].w * wv[b].w;
    }
}

__global__ __launch_bounds__(256, 4) void k_node(const float* __restrict__ E,
                                                 const float* __restrict__ E2,
                                                 const float* __restrict__ Wm,
                                                 const float* __restrict__ bm,
                                                 const float* __restrict__ AW,
                                                 const float* __restrict__ ab,
                                                 const float* __restrict__ qw,
                                                 float* __restrict__ b1buf,
                                                 const float* __restrict__ b2buf,
                                                 int NN) {
  __shared__ float TA[64 * TS];     // E2 tile -> ZN tile (node-major)
  __shared__ float TB[64 * TS];     // H tile  -> ZP tile (node-major)
  __shared__ float b0s[64], b1s[64], abs_[64], qs[64];

  int tid = threadIdx.x;
  int tx = tid & 15, ty = tid >> 4;        // ty 0..15
  int lrow = tid >> 2;                     // staging row 0..63
  int lcol = (tid & 3) * 16;               // staging col base
  int node0 = blockIdx.x * 64;
  int snode = node0 + lrow;
  bool sok = snode < NN;
  const float4 z4 = make_float4(0.f, 0.f, 0.f, 0.f);

  if (tid < 64) { b0s[tid] = bm[tid]; b1s[tid] = bm[64 + tid]; abs_[tid] = ab[tid]; qs[tid] = qw[tid]; }
  {
    const float* sp = E2 + (size_t)snode * 64 + lcol;
#pragma unroll
    for (int c = 0; c < 4; ++c)
      *(float4*)&TA[lrow * TS + lcol + 4 * c] = sok ? *(const float4*)(sp + 4 * c) : z4;
  }
  __syncthreads();

  const float* W0g = Wm;            // [64][64] k-contiguous
  const float* W1g = Wm + 4096;
  float acc[4][4];

  // GEMM1: acc = E2 @ W0^T + b0   (TA b128 reads, W0 from global/L1)
#pragma unroll
  for (int a = 0; a < 4; ++a)
#pragma unroll
    for (int b = 0; b < 4; ++b) acc[a][b] = b0s[tx + 16 * b];
#pragma unroll 2
  for (int kc = 0; kc < 16; ++kc) {
    float4 xv[4], wv[4];
#pragma unroll
    for (int a = 0; a < 4; ++a) xv[a] = *(const float4*)&TA[(ty + 16 * a) * TS + kc * 4];
#pragma unroll
    for (int b = 0; b < 4; ++b) wv[b] = *(const float4*)&W0g[(tx + 16 * b) * 64 + kc * 4];
    dot4(acc, xv, wv);
  }
  // write H = relu(acc) into TB
#pragma unroll
  for (int a = 0; a < 4; ++a)
#pragma unroll
    for (int b = 0; b < 4; ++b)
      TB[(ty + 16 * a) * TS + tx + 16 * b] = fmaxf(acc[a][b], 0.f);
  __syncthreads();

  // GEMM2: acc = H @ W1^T + b1
#pragma unroll
  for (int a = 0; a < 4; ++a)
#pragma unroll
    for (int b = 0; b < 4; ++b) acc[a][b] = b1s[tx + 16 * b];
#pragma unroll 2
  for (int kc = 0; kc < 16; ++kc) {
    float4 xv[4], wv[4];
#pragma unroll
    for (int a = 0; a < 4; ++a) xv[a] = *(const float4*)&TB[(ty + 16 * a) * TS + kc * 4];
#pragma unroll
    for (int b = 0; b < 4; ++b) wv[b] = *(const float4*)&W1g[(tx + 16 * b) * 64 + kc * 4];
    dot4(acc, xv, wv);
  }
  __syncthreads();   // all TA (E2) reads done since GEMM1; TB (H) reads done

  // ZN = relu(acc) -> TA; ZP = (E+b1+b2)/3 -> TB
#pragma unroll
  for (int a = 0; a < 4; ++a)
#pragma unroll
    for (int b = 0; b < 4; ++b)
      TA[(ty + 16 * a) * TS + tx + 16 * b] = fmaxf(acc[a][b], 0.f);
  {
    const float* pe = E + (size_t)snode * 64 + lcol;
    const float* p1 = b1buf + (size_t)snode * 64 + lcol;
    const float* p2 = b2buf + (size_t)snode * 64 + lcol;
#pragma unroll
    for (int c = 0; c < 4; ++c) {
      float4 e4 = sok ? *(const float4*)(pe + 4 * c) : z4;
      float4 a4 = sok ? *(const float4*)(p1 + 4 * c) : z4;
      float4 c4 = sok ? *(const float4*)(p2 + 4 * c) : z4;
      float4 o;
      o.x = (e4.x + a4.x + c4.x) * (1.f / 3.f);
      o.y = (e4.y + a4.y + c4.y) * (1.f / 3.f);
      o.z = (e4.z + a4.z + c4.z) * (1.f / 3.f);
      o.w = (e4.w + a4.w + c4.w) * (1.f / 3.f);
      *(float4*)&TB[lrow * TS + lcol + 4 * c] = o;
    }
  }
  __syncthreads();

  // Attention GEMMs: ac1 = ZP@AW^T+ab (TB), ac2 = ZN@AW^T+ab (TA)
  float ac1[4][4], ac2[4][4];
#pragma unroll
  for (int a = 0; a < 4; ++a)
#pragma unroll
    for (int b = 0; b < 4; ++b) { ac1[a][b] = abs_[tx + 16 * b]; ac2[a][b] = ac1[a][b]; }
#pragma unroll 2
  for (int kc = 0; kc < 16; ++kc) {
    float4 zp[4], zn[4], wv[4];
#pragma unroll
    for (int a = 0; a < 4; ++a) {
      zp[a] = *(const float4*)&TB[(ty + 16 * a) * TS + kc * 4];
      zn[a] = *(const float4*)&TA[(ty + 16 * a) * TS + kc * 4];
    }
#pragma unroll
    for (int b = 0; b < 4; ++b) wv[b] = *(const float4*)&AW[(tx + 16 * b) * 64 + kc * 4];
    dot4(ac1, zp, wv);
    dot4(ac2, zn, wv);
  }

  // per-node q-dots of tanh + 16-lane shfl reduce (tx-lanes are consecutive)
  float a0v[4], a1v[4];
#pragma unroll
  for (int a = 0; a < 4; ++a) {
    float p1 = 0.f, p2 = 0.f;
#pragma unroll
    for (int b = 0; b < 4; ++b) {
      float q = qs[tx + 16 * b];
      p1 += fast_tanh(ac1[a][b]) * q;
      p2 += fast_tanh(ac2[a][b]) * q;
    }
#pragma unroll
    for (int off = 8; off; off >>= 1) {
      p1 += __shfl_xor(p1, off);
      p2 += __shfl_xor(p2, off);
    }
    float m = fmaxf(p1, p2);
    float e1 = __expf(p1 - m), e2 = __expf(p2 - m);
    float inv = 1.f / (e1 + e2);
    a0v[a] = e1 * inv;
    a1v[a] = e2 * inv;
  }

  // epilogue: Z = a0*ZP + a1*ZN directly to global
#pragma unroll
  for (int a = 0; a < 4; ++a) {
    int node = node0 + ty + 16 * a;
    if (node < NN) {
      float* op = b1buf + (size_t)node * 64;
#pragma unroll
      for (int b = 0; b < 4; ++b) {
        int col = tx + 16 * b;
        int base = (ty + 16 * a) * TS + col;
        op[col] = a0v[a] * TB[base] + a1v[a] * TA[base];
      }
    }
  }
}

// 16-lane sub-group per batch element; block handles 16; grid = ceil(B/16)
__global__ __launch_bounds__(256) void k_score(const float* __restrict__ Z,
                                               const int* __restrict__ u,
                                               const int* __restrict__ v,
                                               const int* __restrict__ n,
                                               const float* __restrict__ w,
                                               float* __restrict__ out, int B, int K) {
  __shared__ float xbuf[16][65];   // K <= 64
  __shared__ float part[16];
  int t = threadIdx.x;
  int wv = t >> 6, lane = t & 63;
  int sg = lane >> 4, sl = lane & 15;
  int bloc = wv * 4 + sg;
  int b = blockIdx.x * 16 + bloc;
  float lossb = 0.f;
  if (b < B) {
    int uid = u[b], vid = v[b];
    float4 u4 = *(const float4*)&Z[(size_t)uid * 64 + sl * 4];
    float4 v4 = *(const float4*)&Z[(size_t)vid * 64 + sl * 4];
    float p = u4.x * v4.x + u4.y * v4.y + u4.z * v4.z + u4.w * v4.w;
#pragma unroll
    for (int off = 8; off; off >>= 1) p += __shfl_xor(p, off);
    float wb = w[b];
    float sgn = (wb > 0.f) ? 1.f : ((wb < 0.f) ? -1.f : 0.f);
    float sp = sgn * p;
    float regl = u4.x * u4.x + u4.y * u4.y + u4.z * u4.z + u4.w * u4.w
               + v4.x * v4.x + v4.y * v4.y + v4.z * v4.z + v4.w * v4.w;
    const int* nb_ = n + (size_t)b * K;
    for (int k = 0; k < K; ++k) {
      int nid = nb_[k];
      float4 n4 = *(const float4*)&Z[(size_t)nid * 64 + sl * 4];
      float d = u4.x * n4.x + u4.y * n4.y + u4.z * n4.z + u4.w * n4.w;
      regl += n4.x * n4.x + n4.y * n4.y + n4.z * n4.z + n4.w * n4.w;
#pragma unroll
      for (int off = 8; off; off >>= 1) d += __shfl_xor(d, off);
      if (sl == 0) xbuf[bloc][k] = sp - d;
    }
#pragma unroll
    for (int off = 8; off; off >>= 1) regl += __shfl_xor(regl, off);
    float sb = 0.f;
    for (int k = sl; k < K; k += 16) {
      float x = xbuf[bloc][k];
      sb += fminf(x, 0.f) - log1pf(expf(-fabsf(x)));
    }
#pragma unroll
    for (int off = 8; off; off >>= 1) sb += __shfl_xor(sb, off);
    lossb = -sb + 1e-4f * regl;
  }
  if (sl == 0) part[bloc] = (b < B) ? lossb : 0.f;
  __syncthreads();
  if (t == 0) {
    float s = 0.f;
#pragma unroll
    for (int i = 0; i < 16; ++i) s += part[i];
    unsafeAtomicAdd(out, s);
  }
}

extern "C" void kernel_launch(void* const* d_in, const int* in_sizes, int n_in,
                              void* d_out, int out_size, void* d_ws, size_t ws_size,
                              hipStream_t stream) {
  const float* E  = (const float*)d_in[0];
  const float* E2 = (const float*)d_in[1];
  const float* Wm = (const float*)d_in[2];
  const float* bm = (const float*)d_in[3];
  const float* AW = (const float*)d_in[4];
  const float* ab = (const float*)d_in[5];
  const float* qw = (const float*)d_in[6];
  const int*   ei = (const int*)d_in[7];
  const int*   u  = (const int*)d_in[8];
  const int*   v  = (const int*)d_in[9];
  const int*   nn = (const int*)d_in[10];
  const float* w  = (const float*)d_in[11];

  const int NN = in_sizes[0] / 64;        // 150000
  const int NE = in_sizes[7] / 2;         // 3200000
  const int B  = in_sizes[8];             // 16384
  const int K  = in_sizes[10] / B;        // 40

  const int* src = ei;
  const int* dst = ei + NE;

  // workspace layout
  float* ws     = (float*)d_ws;
  float* dinv   = ws;                         // NN floats
  float* b1     = dinv + NN;                  // NN*64
  float* b2     = b1 + (size_t)NN * 64;       // NN*64
  int*   deg_i  = (int*)(b2 + (size_t)NN * 64);   // NN ints
  int*   rowptr = deg_i + NN;                 // NN+1 ints
  int*   bsum   = rowptr + NN + 1;            // <=1024 ints
  int*   csrc   = bsum + 1024;                // NE ints
  int*   rank   = csrc + NE;                  // NE ints
  float* outf   = (float*)d_out;

  const int nb = (NN + 255) / 256;            // scan blocks (<=1024)

  hipMemsetAsync(deg_i, 0, (size_t)NN * sizeof(int), stream);
  hipMemsetAsync(outf, 0, sizeof(float), stream);

  k_count<<<(NE + 255) / 256, 256, 0, stream>>>(dst, deg_i, rank, NE);
  k_scan1<<<nb, 256, 0, stream>>>(deg_i, bsum, NN);
  k_scan2<<<1, 1024, 0, stream>>>(bsum, nb);
  k_scan3<<<nb, 256, 0, stream>>>(deg_i, bsum, rowptr, NN);
  k_dinv<<<(NN + 255) / 256, 256, 0, stream>>>(deg_i, dinv, NN);
  k_scatter<<<(NE + 255) / 256, 256, 0, stream>>>(src, dst, rowptr, rank, csrc, NE);

  int gatherBlocks = ((size_t)NN * 16 + 255) / 256;   // 16 lanes per node
  k_gather<<<gatherBlocks, 256, 0, stream>>>(E, rowptr, csrc, dinv, b1, NN);
  k_gather<<<gatherBlocks, 256, 0, stream>>>(b1, rowptr, csrc, dinv, b2, NN);

  int nodeTiles = (NN + 63) / 64;
  k_node<<<nodeTiles, 256, 0, stream>>>(E, E2, Wm, bm, AW, ab, qw, b1, b2, NN);

  k_score<<<(B + 15) / 16, 256, 0, stream>>>(b1, u, v, nn, w, outf, B, K);
}

// Round 11
// 611.518 us; speedup vs baseline: 1.2571x; 1.2571x over previous
//
#include <hip/hip_runtime.h>
#include <math.h>

// ---------------------------------------------------------------------------
// SiReN loss on MI355X — round 11: k_node = round-9 LDS-weight structure
// + col-major weight buffer (float4 staging) + b128 k-chunked reads (TS=68).
// ---------------------------------------------------------------------------

// count + per-edge rank within its dst bucket (arrival order)
__global__ void k_count(const int* __restrict__ dst, int* __restrict__ deg,
                        int* __restrict__ rank, int NE) {
  int e = blockIdx.x * blockDim.x + threadIdx.x;
  if (e < NE) rank[e] = atomicAdd(&deg[dst[e]], 1);
}

__global__ void k_scan1(const int* __restrict__ deg, int* __restrict__ bsum, int NN) {
  __shared__ int sm[256];
  int t = threadIdx.x;
  int i = blockIdx.x * 256 + t;
  sm[t] = (i < NN) ? deg[i] : 0;
  __syncthreads();
  for (int s = 128; s > 0; s >>= 1) {
    if (t < s) sm[t] += sm[t + s];
    __syncthreads();
  }
  if (t == 0) bsum[blockIdx.x] = sm[0];
}

__global__ void k_scan2(int* __restrict__ bsum, int nb) {
  __shared__ int sm[1024];
  int t = threadIdx.x;
  int v = (t < nb) ? bsum[t] : 0;
  sm[t] = v;
  __syncthreads();
  for (int off = 1; off < 1024; off <<= 1) {
    int add = (t >= off) ? sm[t - off] : 0;
    __syncthreads();
    sm[t] += add;
    __syncthreads();
  }
  if (t < nb) bsum[t] = sm[t] - v;  // exclusive
}

__global__ void k_scan3(const int* __restrict__ deg, const int* __restrict__ bsum,
                        int* __restrict__ rowptr, int NN) {
  __shared__ int sm[256];
  int t = threadIdx.x;
  int i = blockIdx.x * 256 + t;
  int v = (i < NN) ? deg[i] : 0;
  sm[t] = v;
  __syncthreads();
  for (int off = 1; off < 256; off <<= 1) {
    int add = (t >= off) ? sm[t - off] : 0;
    __syncthreads();
    sm[t] += add;
    __syncthreads();
  }
  int incl = sm[t] + bsum[blockIdx.x];
  if (i < NN) rowptr[i] = incl - v;
  if (i == NN - 1) rowptr[NN] = incl;
}

__global__ void k_dinv(const int* __restrict__ deg, float* __restrict__ dinv, int NN) {
  int i = blockIdx.x * blockDim.x + threadIdx.x;
  if (i < NN) {
    int d = deg[i];
    dinv[i] = (d > 0) ? rsqrtf((float)d) : 0.f;
  }
}

// atomic-free scatter: pos = rowptr[dst] + rank
__global__ void k_scatter(const int* __restrict__ src, const int* __restrict__ dst,
                          const int* __restrict__ rowptr, const int* __restrict__ rank,
                          int* __restrict__ csrc, int NE) {
  int e = blockIdx.x * blockDim.x + threadIdx.x;
  if (e >= NE) return;
  int d = dst[e];
  csrc[rowptr[d] + rank[e]] = src[e];
}

// 16-lane sub-group per node, lane = 4 dims (float4); 4 nodes per wave
__global__ __launch_bounds__(256) void k_gather(const float* __restrict__ x,
                                                const int* __restrict__ rowptr,
                                                const int* __restrict__ csrc,
                                                const float* __restrict__ dinv,
                                                float* __restrict__ out, int NN) {
  int gid = blockIdx.x * blockDim.x + threadIdx.x;
  int node = gid >> 4;
  if (node >= NN) return;
  int sl = gid & 15;
  int beg = rowptr[node], end = rowptr[node + 1];
  float dn = dinv[node];
  float ax = 0.f, ay = 0.f, az = 0.f, aw = 0.f;
  int i = beg;
  for (; i + 1 < end; i += 2) {
    int s0 = csrc[i], s1 = csrc[i + 1];
    float n0 = dinv[s0], n1 = dinv[s1];
    float4 x0 = *(const float4*)&x[(size_t)s0 * 64 + sl * 4];
    float4 x1 = *(const float4*)&x[(size_t)s1 * 64 + sl * 4];
    ax += n0 * x0.x; ay += n0 * x0.y; az += n0 * x0.z; aw += n0 * x0.w;
    ax += n1 * x1.x; ay += n1 * x1.y; az += n1 * x1.z; aw += n1 * x1.w;
  }
  if (i < end) {
    int s0 = csrc[i];
    float n0 = dinv[s0];
    float4 x0 = *(const float4*)&x[(size_t)s0 * 64 + sl * 4];
    ax += n0 * x0.x; ay += n0 * x0.y; az += n0 * x0.z; aw += n0 * x0.w;
  }
  float4 r; r.x = ax * dn; r.y = ay * dn; r.z = az * dn; r.w = aw * dn;
  *(float4*)&out[(size_t)node * 64 + sl * 4] = r;
}

// ---------------------------------------------------------------------------
// k_node v6: 64-node tile; 4x4 register tile; single LDS weight buffer Wl
// (col-major, stride 68, float4-staged, re-staged W0->W1->AW); all inner-loop
// reads are ds_read_b128 at stride 68 (2-way max = free).
// LDS = 3 x 64*68*4B = 52.2 KB -> 3 blocks/CU.
// ---------------------------------------------------------------------------
#define TS 68

__device__ inline float fast_tanh(float x) {
  float t = __expf(fminf(fmaxf(2.f * x, -30.f), 30.f));
  return (t - 1.f) / (t + 1.f);
}

__device__ inline void dot4(float acc[4][4], const float4 xv[4], const float4 wv[4]) {
#pragma unroll
  for (int a = 0; a < 4; ++a)
#pragma unroll
    for (int b = 0; b < 4; ++b) {
      acc[a][b] += xv[a].x * wv[b].x;
      acc[a][b] += xv[a].y * wv[b].y;
      acc[a][b] += xv[a].z * wv[b].z;
      acc[a][b] += xv[a].w * wv[b].w;
    }
}

__global__ __launch_bounds__(256, 4) void k_node(const float* __restrict__ E,
                                                 const float* __restrict__ E2,
                                                 const float* __restrict__ Wm,
                                                 const float* __restrict__ bm,
                                                 const float* __restrict__ AW,
                                                 const float* __restrict__ ab,
                                                 const float* __restrict__ qw,
                                                 float* __restrict__ b1buf,
                                                 const float* __restrict__ b2buf,
                                                 int NN) {
  __shared__ __align__(16) float Wl[64 * TS];  // weight, col-major: Wl[col*TS + k]
  __shared__ __align__(16) float TA[64 * TS];  // E2 tile -> ZN tile (node-major)
  __shared__ __align__(16) float TB[64 * TS];  // H tile  -> ZP tile (node-major)
  __shared__ float b0s[64], b1s[64], abs_[64], qs[64];

  int tid = threadIdx.x;
  int tx = tid & 15, ty = tid >> 4;        // ty 0..15
  int lrow = tid >> 2;                     // staging row 0..63
  int lcol = (tid & 3) * 16;               // staging col base
  int node0 = blockIdx.x * 64;
  int snode = node0 + lrow;
  bool sok = snode < NN;
  const float4 z4 = make_float4(0.f, 0.f, 0.f, 0.f);

  // stage W0 (col-major float4: read Wm[col][k] contiguous, write contiguous)
  for (int idx = tid; idx < 1024; idx += 256) {
    int col = idx >> 4, kc = idx & 15;
    *(float4*)&Wl[col * TS + kc * 4] = *(const float4*)&Wm[col * 64 + kc * 4];
  }
  if (tid < 64) { b0s[tid] = bm[tid]; b1s[tid] = bm[64 + tid]; abs_[tid] = ab[tid]; qs[tid] = qw[tid]; }
  {
    const float* sp = E2 + (size_t)snode * 64 + lcol;
#pragma unroll
    for (int c = 0; c < 4; ++c)
      *(float4*)&TA[lrow * TS + lcol + 4 * c] = sok ? *(const float4*)(sp + 4 * c) : z4;
  }
  __syncthreads();

  float acc[4][4];

  // GEMM1: acc = E2 @ W0^T + b0   (all b128)
#pragma unroll
  for (int a = 0; a < 4; ++a)
#pragma unroll
    for (int b = 0; b < 4; ++b) acc[a][b] = b0s[tx + 16 * b];
#pragma unroll 2
  for (int kc = 0; kc < 16; ++kc) {
    float4 xv[4], wv[4];
#pragma unroll
    for (int a = 0; a < 4; ++a) xv[a] = *(const float4*)&TA[(ty + 16 * a) * TS + kc * 4];
#pragma unroll
    for (int b = 0; b < 4; ++b) wv[b] = *(const float4*)&Wl[(tx + 16 * b) * TS + kc * 4];
    dot4(acc, xv, wv);
  }
  __syncthreads();   // Wl (W0) reads done

  // re-stage Wl = W1; write H = relu(acc) into TB
  for (int idx = tid; idx < 1024; idx += 256) {
    int col = idx >> 4, kc = idx & 15;
    *(float4*)&Wl[col * TS + kc * 4] = *(const float4*)&Wm[4096 + col * 64 + kc * 4];
  }
#pragma unroll
  for (int a = 0; a < 4; ++a)
#pragma unroll
    for (int b = 0; b < 4; ++b)
      TB[(ty + 16 * a) * TS + tx + 16 * b] = fmaxf(acc[a][b], 0.f);
  __syncthreads();

  // GEMM2: acc = H @ W1^T + b1
#pragma unroll
  for (int a = 0; a < 4; ++a)
#pragma unroll
    for (int b = 0; b < 4; ++b) acc[a][b] = b1s[tx + 16 * b];
#pragma unroll 2
  for (int kc = 0; kc < 16; ++kc) {
    float4 xv[4], wv[4];
#pragma unroll
    for (int a = 0; a < 4; ++a) xv[a] = *(const float4*)&TB[(ty + 16 * a) * TS + kc * 4];
#pragma unroll
    for (int b = 0; b < 4; ++b) wv[b] = *(const float4*)&Wl[(tx + 16 * b) * TS + kc * 4];
    dot4(acc, xv, wv);
  }
  __syncthreads();   // Wl (W1) + TB (H) reads done

  // re-stage Wl = AW; ZN = relu(acc) -> TA; ZP = (E+b1+b2)/3 -> TB
  for (int idx = tid; idx < 1024; idx += 256) {
    int col = idx >> 4, kc = idx & 15;
    *(float4*)&Wl[col * TS + kc * 4] = *(const float4*)&AW[col * 64 + kc * 4];
  }
#pragma unroll
  for (int a = 0; a < 4; ++a)
#pragma unroll
    for (int b = 0; b < 4; ++b)
      TA[(ty + 16 * a) * TS + tx + 16 * b] = fmaxf(acc[a][b], 0.f);
  {
    const float* pe = E + (size_t)snode * 64 + lcol;
    const float* p1 = b1buf + (size_t)snode * 64 + lcol;
    const float* p2 = b2buf + (size_t)snode * 64 + lcol;
#pragma unroll
    for (int c = 0; c < 4; ++c) {
      float4 e4 = sok ? *(const float4*)(pe + 4 * c) : z4;
      float4 a4 = sok ? *(const float4*)(p1 + 4 * c) : z4;
      float4 c4 = sok ? *(const float4*)(p2 + 4 * c) : z4;
      float4 o;
      o.x = (e4.x + a4.x + c4.x) * (1.f / 3.f);
      o.y = (e4.y + a4.y + c4.y) * (1.f / 3.f);
      o.z = (e4.z + a4.z + c4.z) * (1.f / 3.f);
      o.w = (e4.w + a4.w + c4.w) * (1.f / 3.f);
      *(float4*)&TB[lrow * TS + lcol + 4 * c] = o;
    }
  }
  __syncthreads();

  // Attention GEMMs: ac1 = ZP@AW^T+ab (TB), ac2 = ZN@AW^T+ab (TA)
  float ac1[4][4], ac2[4][4];
#pragma unroll
  for (int a = 0; a < 4; ++a)
#pragma unroll
    for (int b = 0; b < 4; ++b) { ac1[a][b] = abs_[tx + 16 * b]; ac2[a][b] = ac1[a][b]; }
#pragma unroll 2
  for (int kc = 0; kc < 16; ++kc) {
    float4 zp[4], zn[4], wv[4];
#pragma unroll
    for (int a = 0; a < 4; ++a) {
      zp[a] = *(const float4*)&TB[(ty + 16 * a) * TS + kc * 4];
      zn[a] = *(const float4*)&TA[(ty + 16 * a) * TS + kc * 4];
    }
#pragma unroll
    for (int b = 0; b < 4; ++b) wv[b] = *(const float4*)&Wl[(tx + 16 * b) * TS + kc * 4];
    dot4(ac1, zp, wv);
    dot4(ac2, zn, wv);
  }

  // per-node q-dots of tanh + 16-lane shfl reduce (tx-lanes are consecutive)
  float a0v[4], a1v[4];
#pragma unroll
  for (int a = 0; a < 4; ++a) {
    float p1 = 0.f, p2 = 0.f;
#pragma unroll
    for (int b = 0; b < 4; ++b) {
      float q = qs[tx + 16 * b];
      p1 += fast_tanh(ac1[a][b]) * q;
      p2 += fast_tanh(ac2[a][b]) * q;
    }
#pragma unroll
    for (int off = 8; off; off >>= 1) {
      p1 += __shfl_xor(p1, off);
      p2 += __shfl_xor(p2, off);
    }
    float m = fmaxf(p1, p2);
    float e1 = __expf(p1 - m), e2 = __expf(p2 - m);
    float inv = 1.f / (e1 + e2);
    a0v[a] = e1 * inv;
    a1v[a] = e2 * inv;
  }

  // epilogue: Z = a0*ZP + a1*ZN directly to global
#pragma unroll
  for (int a = 0; a < 4; ++a) {
    int node = node0 + ty + 16 * a;
    if (node < NN) {
      float* op = b1buf + (size_t)node * 64;
#pragma unroll
      for (int b = 0; b < 4; ++b) {
        int col = tx + 16 * b;
        int base = (ty + 16 * a) * TS + col;
        op[col] = a0v[a] * TB[base] + a1v[a] * TA[base];
      }
    }
  }
}

// 16-lane sub-group per batch element; block handles 16; grid = ceil(B/16)
__global__ __launch_bounds__(256) void k_score(const float* __restrict__ Z,
                                               const int* __restrict__ u,
                                               const int* __restrict__ v,
                                               const int* __restrict__ n,
                                               const float* __restrict__ w,
                                               float* __restrict__ out, int B, int K) {
  __shared__ float xbuf[16][65];   // K <= 64
  __shared__ float part[16];
  int t = threadIdx.x;
  int wv = t >> 6, lane = t & 63;
  int sg = lane >> 4, sl = lane & 15;
  int bloc = wv * 4 + sg;
  int b = blockIdx.x * 16 + bloc;
  float lossb = 0.f;
  if (b < B) {
    int uid = u[b], vid = v[b];
    float4 u4 = *(const float4*)&Z[(size_t)uid * 64 + sl * 4];
    float4 v4 = *(const float4*)&Z[(size_t)vid * 64 + sl * 4];
    float p = u4.x * v4.x + u4.y * v4.y + u4.z * v4.z + u4.w * v4.w;
#pragma unroll
    for (int off = 8; off; off >>= 1) p += __shfl_xor(p, off);
    float wb = w[b];
    float sgn = (wb > 0.f) ? 1.f : ((wb < 0.f) ? -1.f : 0.f);
    float sp = sgn * p;
    float regl = u4.x * u4.x + u4.y * u4.y + u4.z * u4.z + u4.w * u4.w
               + v4.x * v4.x + v4.y * v4.y + v4.z * v4.z + v4.w * v4.w;
    const int* nb_ = n + (size_t)b * K;
    for (int k = 0; k < K; ++k) {
      int nid = nb_[k];
      float4 n4 = *(const float4*)&Z[(size_t)nid * 64 + sl * 4];
      float d = u4.x * n4.x + u4.y * n4.y + u4.z * n4.z + u4.w * n4.w;
      regl += n4.x * n4.x + n4.y * n4.y + n4.z * n4.z + n4.w * n4.w;
#pragma unroll
      for (int off = 8; off; off >>= 1) d += __shfl_xor(d, off);
      if (sl == 0) xbuf[bloc][k] = sp - d;
    }
#pragma unroll
    for (int off = 8; off; off >>= 1) regl += __shfl_xor(regl, off);
    float sb = 0.f;
    for (int k = sl; k < K; k += 16) {
      float x = xbuf[bloc][k];
      sb += fminf(x, 0.f) - log1pf(expf(-fabsf(x)));
    }
#pragma unroll
    for (int off = 8; off; off >>= 1) sb += __shfl_xor(sb, off);
    lossb = -sb + 1e-4f * regl;
  }
  if (sl == 0) part[bloc] = (b < B) ? lossb : 0.f;
  __syncthreads();
  if (t == 0) {
    float s = 0.f;
#pragma unroll
    for (int i = 0; i < 16; ++i) s += part[i];
    unsafeAtomicAdd(out, s);
  }
}

extern "C" void kernel_launch(void* const* d_in, const int* in_sizes, int n_in,
                              void* d_out, int out_size, void* d_ws, size_t ws_size,
                              hipStream_t stream) {
  const float* E  = (const float*)d_in[0];
  const float* E2 = (const float*)d_in[1];
  const float* Wm = (const float*)d_in[2];
  const float* bm = (const float*)d_in[3];
  const float* AW = (const float*)d_in[4];
  const float* ab = (const float*)d_in[5];
  const float* qw = (const float*)d_in[6];
  const int*   ei = (const int*)d_in[7];
  const int*   u  = (const int*)d_in[8];
  const int*   v  = (const int*)d_in[9];
  const int*   nn = (const int*)d_in[10];
  const float* w  = (const float*)d_in[11];

  const int NN = in_sizes[0] / 64;        // 150000
  const int NE = in_sizes[7] / 2;         // 3200000
  const int B  = in_sizes[8];             // 16384
  const int K  = in_sizes[10] / B;        // 40

  const int* src = ei;
  const int* dst = ei + NE;

  // workspace layout
  float* ws     = (float*)d_ws;
  float* dinv   = ws;                         // NN floats
  float* b1     = dinv + NN;                  // NN*64
  float* b2     = b1 + (size_t)NN * 64;       // NN*64
  int*   deg_i  = (int*)(b2 + (size_t)NN * 64);   // NN ints
  int*   rowptr = deg_i + NN;                 // NN+1 ints
  int*   bsum   = rowptr + NN + 1;            // <=1024 ints
  int*   csrc   = bsum + 1024;                // NE ints
  int*   rank   = csrc + NE;                  // NE ints
  float* outf   = (float*)d_out;

  const int nb = (NN + 255) / 256;            // scan blocks (<=1024)

  hipMemsetAsync(deg_i, 0, (size_t)NN * sizeof(int), stream);
  hipMemsetAsync(outf, 0, sizeof(float), stream);

  k_count<<<(NE + 255) / 256, 256, 0, stream>>>(dst, deg_i, rank, NE);
  k_scan1<<<nb, 256, 0, stream>>>(deg_i, bsum, NN);
  k_scan2<<<1, 1024, 0, stream>>>(bsum, nb);
  k_scan3<<<nb, 256, 0, stream>>>(deg_i, bsum, rowptr, NN);
  k_dinv<<<(NN + 255) / 256, 256, 0, stream>>>(deg_i, dinv, NN);
  k_scatter<<<(NE + 255) / 256, 256, 0, stream>>>(src, dst, rowptr, rank, csrc, NE);

  int gatherBlocks = ((size_t)NN * 16 + 255) / 256;   // 16 lanes per node
  k_gather<<<gatherBlocks, 256, 0, stream>>>(E, rowptr, csrc, dinv, b1, NN);
  k_gather<<<gatherBlocks, 256, 0, stream>>>(b1, rowptr, csrc, dinv, b2, NN);

  int nodeTiles = (NN + 63) / 64;
  k_node<<<nodeTiles, 256, 0, stream>>>(E, E2, Wm, bm, AW, ab, qw, b1, b2, NN);

  k_score<<<(B + 15) / 16, 256, 0, stream>>>(b1, u, v, nn, w, outf, B, K);
}

// Round 12
// 520.899 us; speedup vs baseline: 1.4758x; 1.1740x over previous
//
#include <hip/hip_runtime.h>
#include <math.h>

// ---------------------------------------------------------------------------
// SiReN loss on MI355X — round 12: bf16 propagation.
// E -> bf16 once; both gathers move 128B rows (half traffic), f32 accumulate,
// 4x unrolled edge loop; k_node reads bf16 b1/b2, writes f32 Z buffer.
// Workspace (floats): [dinv NN][Zf NN*64][Eh NN*32][b1h NN*32][b2h NN*32]
//                     [deg NN][rowptr NN+1][bsum 1024][csrc NE][rank NE]
// ---------------------------------------------------------------------------

typedef unsigned int uint;
typedef unsigned short ushort;

__device__ inline float b2f(ushort u) { return __uint_as_float(((uint)u) << 16); }
__device__ inline ushort f2b(float f) {
  uint u = __float_as_uint(f);
  return (ushort)((u + 0x7fffu + ((u >> 16) & 1u)) >> 16);
}
__device__ inline uint pack2(float lo, float hi) {
  return (uint)f2b(lo) | ((uint)f2b(hi) << 16);
}

// f32 -> bf16 converter: thread handles 8 elems
__global__ void k_half(const float* __restrict__ x, ushort* __restrict__ out, int n8) {
  int i = blockIdx.x * blockDim.x + threadIdx.x;
  if (i >= n8) return;
  const float4* p = (const float4*)(x + (size_t)i * 8);
  float4 a = p[0], b = p[1];
  uint4 o;
  o.x = pack2(a.x, a.y); o.y = pack2(a.z, a.w);
  o.z = pack2(b.x, b.y); o.w = pack2(b.z, b.w);
  ((uint4*)out)[i] = o;
}

// count + per-edge rank within its dst bucket (arrival order)
__global__ void k_count(const int* __restrict__ dst, int* __restrict__ deg,
                        int* __restrict__ rank, int NE) {
  int e = blockIdx.x * blockDim.x + threadIdx.x;
  if (e < NE) rank[e] = atomicAdd(&deg[dst[e]], 1);
}

__global__ void k_scan1(const int* __restrict__ deg, int* __restrict__ bsum, int NN) {
  __shared__ int sm[256];
  int t = threadIdx.x;
  int i = blockIdx.x * 256 + t;
  sm[t] = (i < NN) ? deg[i] : 0;
  __syncthreads();
  for (int s = 128; s > 0; s >>= 1) {
    if (t < s) sm[t] += sm[t + s];
    __syncthreads();
  }
  if (t == 0) bsum[blockIdx.x] = sm[0];
}

__global__ void k_scan2(int* __restrict__ bsum, int nb) {
  __shared__ int sm[1024];
  int t = threadIdx.x;
  int v = (t < nb) ? bsum[t] : 0;
  sm[t] = v;
  __syncthreads();
  for (int off = 1; off < 1024; off <<= 1) {
    int add = (t >= off) ? sm[t - off] : 0;
    __syncthreads();
    sm[t] += add;
    __syncthreads();
  }
  if (t < nb) bsum[t] = sm[t] - v;  // exclusive
}

__global__ void k_scan3(const int* __restrict__ deg, const int* __restrict__ bsum,
                        int* __restrict__ rowptr, int NN) {
  __shared__ int sm[256];
  int t = threadIdx.x;
  int i = blockIdx.x * 256 + t;
  int v = (i < NN) ? deg[i] : 0;
  sm[t] = v;
  __syncthreads();
  for (int off = 1; off < 256; off <<= 1) {
    int add = (t >= off) ? sm[t - off] : 0;
    __syncthreads();
    sm[t] += add;
    __syncthreads();
  }
  int incl = sm[t] + bsum[blockIdx.x];
  if (i < NN) rowptr[i] = incl - v;
  if (i == NN - 1) rowptr[NN] = incl;
}

__global__ void k_dinv(const int* __restrict__ deg, float* __restrict__ dinv, int NN) {
  int i = blockIdx.x * blockDim.x + threadIdx.x;
  if (i < NN) {
    int d = deg[i];
    dinv[i] = (d > 0) ? rsqrtf((float)d) : 0.f;
  }
}

// atomic-free scatter: pos = rowptr[dst] + rank
__global__ void k_scatter(const int* __restrict__ src, const int* __restrict__ dst,
                          const int* __restrict__ rowptr, const int* __restrict__ rank,
                          int* __restrict__ csrc, int NE) {
  int e = blockIdx.x * blockDim.x + threadIdx.x;
  if (e >= NE) return;
  int d = dst[e];
  csrc[rowptr[d] + rank[e]] = src[e];
}

// 16-lane sub-group per node; bf16 rows (8B/lane), f32 accumulate, 4x unroll
__global__ __launch_bounds__(256) void k_gather(const ushort* __restrict__ x,
                                                const int* __restrict__ rowptr,
                                                const int* __restrict__ csrc,
                                                const float* __restrict__ dinv,
                                                ushort* __restrict__ out, int NN) {
  int gid = blockIdx.x * blockDim.x + threadIdx.x;
  int node = gid >> 4;
  if (node >= NN) return;
  int sl = gid & 15;
  int beg = rowptr[node], end = rowptr[node + 1];
  float dn = dinv[node];
  float a0 = 0.f, a1 = 0.f, a2 = 0.f, a3 = 0.f;
  int i = beg;
  for (; i + 3 < end; i += 4) {
    int s0 = csrc[i], s1 = csrc[i + 1], s2 = csrc[i + 2], s3 = csrc[i + 3];
    float n0 = dinv[s0], n1 = dinv[s1], n2 = dinv[s2], n3 = dinv[s3];
    ushort4 r0 = *(const ushort4*)&x[(size_t)s0 * 64 + sl * 4];
    ushort4 r1 = *(const ushort4*)&x[(size_t)s1 * 64 + sl * 4];
    ushort4 r2 = *(const ushort4*)&x[(size_t)s2 * 64 + sl * 4];
    ushort4 r3 = *(const ushort4*)&x[(size_t)s3 * 64 + sl * 4];
    a0 += n0 * b2f(r0.x); a1 += n0 * b2f(r0.y); a2 += n0 * b2f(r0.z); a3 += n0 * b2f(r0.w);
    a0 += n1 * b2f(r1.x); a1 += n1 * b2f(r1.y); a2 += n1 * b2f(r1.z); a3 += n1 * b2f(r1.w);
    a0 += n2 * b2f(r2.x); a1 += n2 * b2f(r2.y); a2 += n2 * b2f(r2.z); a3 += n2 * b2f(r2.w);
    a0 += n3 * b2f(r3.x); a1 += n3 * b2f(r3.y); a2 += n3 * b2f(r3.z); a3 += n3 * b2f(r3.w);
  }
  for (; i < end; ++i) {
    int s0 = csrc[i];
    float n0 = dinv[s0];
    ushort4 r0 = *(const ushort4*)&x[(size_t)s0 * 64 + sl * 4];
    a0 += n0 * b2f(r0.x); a1 += n0 * b2f(r0.y); a2 += n0 * b2f(r0.z); a3 += n0 * b2f(r0.w);
  }
  ushort4 o;
  o.x = f2b(a0 * dn); o.y = f2b(a1 * dn); o.z = f2b(a2 * dn); o.w = f2b(a3 * dn);
  *(ushort4*)&out[(size_t)node * 64 + sl * 4] = o;
}

// ---------------------------------------------------------------------------
// k_node: 64-node tile; 4x4 register tile; LDS weight buffer (col-major,
// stride 68, float4-staged, re-staged W0->W1->AW); b128 k-chunked reads.
// bf16 b1/b2 inputs; f32 Z output buffer.
// ---------------------------------------------------------------------------
#define TS 68

__device__ inline float fast_tanh(float x) {
  float t = __expf(fminf(fmaxf(2.f * x, -30.f), 30.f));
  return (t - 1.f) / (t + 1.f);
}

__device__ inline void dot4(float acc[4][4], const float4 xv[4], const float4 wv[4]) {
#pragma unroll
  for (int a = 0; a < 4; ++a)
#pragma unroll
    for (int b = 0; b < 4; ++b) {
      acc[a][b] += xv[a].x * wv[b].x;
      acc[a][b] += xv[a].y * wv[b].y;
      acc[a][b] += xv[a].z * wv[b].z;
      acc[a][b] += xv[a].w * wv[b].w;
    }
}

__global__ __launch_bounds__(256, 4) void k_node(const float* __restrict__ E,
                                                 const float* __restrict__ E2,
                                                 const float* __restrict__ Wm,
                                                 const float* __restrict__ bm,
                                                 const float* __restrict__ AW,
                                                 const float* __restrict__ ab,
                                                 const float* __restrict__ qw,
                                                 const ushort* __restrict__ b1h,
                                                 const ushort* __restrict__ b2h,
                                                 float* __restrict__ Zf,
                                                 int NN) {
  __shared__ __align__(16) float Wl[64 * TS];  // weight, col-major: Wl[col*TS + k]
  __shared__ __align__(16) float TA[64 * TS];  // E2 tile -> ZN tile (node-major)
  __shared__ __align__(16) float TB[64 * TS];  // H tile  -> ZP tile (node-major)
  __shared__ float b0s[64], b1s[64], abs_[64], qs[64];

  int tid = threadIdx.x;
  int tx = tid & 15, ty = tid >> 4;        // ty 0..15
  int lrow = tid >> 2;                     // staging row 0..63
  int lcol = (tid & 3) * 16;               // staging col base
  int node0 = blockIdx.x * 64;
  int snode = node0 + lrow;
  bool sok = snode < NN;
  const float4 z4 = make_float4(0.f, 0.f, 0.f, 0.f);

  // stage W0 (col-major float4)
  for (int idx = tid; idx < 1024; idx += 256) {
    int col = idx >> 4, kc = idx & 15;
    *(float4*)&Wl[col * TS + kc * 4] = *(const float4*)&Wm[col * 64 + kc * 4];
  }
  if (tid < 64) { b0s[tid] = bm[tid]; b1s[tid] = bm[64 + tid]; abs_[tid] = ab[tid]; qs[tid] = qw[tid]; }
  {
    const float* sp = E2 + (size_t)snode * 64 + lcol;
#pragma unroll
    for (int c = 0; c < 4; ++c)
      *(float4*)&TA[lrow * TS + lcol + 4 * c] = sok ? *(const float4*)(sp + 4 * c) : z4;
  }
  __syncthreads();

  float acc[4][4];

  // GEMM1: acc = E2 @ W0^T + b0   (all b128)
#pragma unroll
  for (int a = 0; a < 4; ++a)
#pragma unroll
    for (int b = 0; b < 4; ++b) acc[a][b] = b0s[tx + 16 * b];
#pragma unroll 2
  for (int kc = 0; kc < 16; ++kc) {
    float4 xv[4], wv[4];
#pragma unroll
    for (int a = 0; a < 4; ++a) xv[a] = *(const float4*)&TA[(ty + 16 * a) * TS + kc * 4];
#pragma unroll
    for (int b = 0; b < 4; ++b) wv[b] = *(const float4*)&Wl[(tx + 16 * b) * TS + kc * 4];
    dot4(acc, xv, wv);
  }
  __syncthreads();   // Wl (W0) reads done

  // re-stage Wl = W1; write H = relu(acc) into TB
  for (int idx = tid; idx < 1024; idx += 256) {
    int col = idx >> 4, kc = idx & 15;
    *(float4*)&Wl[col * TS + kc * 4] = *(const float4*)&Wm[4096 + col * 64 + kc * 4];
  }
#pragma unroll
  for (int a = 0; a < 4; ++a)
#pragma unroll
    for (int b = 0; b < 4; ++b)
      TB[(ty + 16 * a) * TS + tx + 16 * b] = fmaxf(acc[a][b], 0.f);
  __syncthreads();

  // GEMM2: acc = H @ W1^T + b1
#pragma unroll
  for (int a = 0; a < 4; ++a)
#pragma unroll
    for (int b = 0; b < 4; ++b) acc[a][b] = b1s[tx + 16 * b];
#pragma unroll 2
  for (int kc = 0; kc < 16; ++kc) {
    float4 xv[4], wv[4];
#pragma unroll
    for (int a = 0; a < 4; ++a) xv[a] = *(const float4*)&TB[(ty + 16 * a) * TS + kc * 4];
#pragma unroll
    for (int b = 0; b < 4; ++b) wv[b] = *(const float4*)&Wl[(tx + 16 * b) * TS + kc * 4];
    dot4(acc, xv, wv);
  }
  __syncthreads();   // Wl (W1) + TB (H) reads done

  // re-stage Wl = AW; ZN = relu(acc) -> TA; ZP = (E+b1+b2)/3 -> TB
  for (int idx = tid; idx < 1024; idx += 256) {
    int col = idx >> 4, kc = idx & 15;
    *(float4*)&Wl[col * TS + kc * 4] = *(const float4*)&AW[col * 64 + kc * 4];
  }
#pragma unroll
  for (int a = 0; a < 4; ++a)
#pragma unroll
    for (int b = 0; b < 4; ++b)
      TA[(ty + 16 * a) * TS + tx + 16 * b] = fmaxf(acc[a][b], 0.f);
  {
    const float* pe = E + (size_t)snode * 64 + lcol;
    const ushort* p1 = b1h + (size_t)snode * 64 + lcol;
    const ushort* p2 = b2h + (size_t)snode * 64 + lcol;
#pragma unroll
    for (int c = 0; c < 4; ++c) {
      float4 e4 = sok ? *(const float4*)(pe + 4 * c) : z4;
      ushort4 q1 = sok ? *(const ushort4*)(p1 + 4 * c) : make_ushort4(0, 0, 0, 0);
      ushort4 q2 = sok ? *(const ushort4*)(p2 + 4 * c) : make_ushort4(0, 0, 0, 0);
      float4 o;
      o.x = (e4.x + b2f(q1.x) + b2f(q2.x)) * (1.f / 3.f);
      o.y = (e4.y + b2f(q1.y) + b2f(q2.y)) * (1.f / 3.f);
      o.z = (e4.z + b2f(q1.z) + b2f(q2.z)) * (1.f / 3.f);
      o.w = (e4.w + b2f(q1.w) + b2f(q2.w)) * (1.f / 3.f);
      *(float4*)&TB[lrow * TS + lcol + 4 * c] = o;
    }
  }
  __syncthreads();

  // Attention GEMMs: ac1 = ZP@AW^T+ab (TB), ac2 = ZN@AW^T+ab (TA)
  float ac1[4][4], ac2[4][4];
#pragma unroll
  for (int a = 0; a < 4; ++a)
#pragma unroll
    for (int b = 0; b < 4; ++b) { ac1[a][b] = abs_[tx + 16 * b]; ac2[a][b] = ac1[a][b]; }
#pragma unroll 2
  for (int kc = 0; kc < 16; ++kc) {
    float4 zp[4], zn[4], wv[4];
#pragma unroll
    for (int a = 0; a < 4; ++a) {
      zp[a] = *(const float4*)&TB[(ty + 16 * a) * TS + kc * 4];
      zn[a] = *(const float4*)&TA[(ty + 16 * a) * TS + kc * 4];
    }
#pragma unroll
    for (int b = 0; b < 4; ++b) wv[b] = *(const float4*)&Wl[(tx + 16 * b) * TS + kc * 4];
    dot4(ac1, zp, wv);
    dot4(ac2, zn, wv);
  }

  // per-node q-dots of tanh + 16-lane shfl reduce (tx-lanes are consecutive)
  float a0v[4], a1v[4];
#pragma unroll
  for (int a = 0; a < 4; ++a) {
    float p1 = 0.f, p2 = 0.f;
#pragma unroll
    for (int b = 0; b < 4; ++b) {
      float q = qs[tx + 16 * b];
      p1 += fast_tanh(ac1[a][b]) * q;
      p2 += fast_tanh(ac2[a][b]) * q;
    }
#pragma unroll
    for (int off = 8; off; off >>= 1) {
      p1 += __shfl_xor(p1, off);
      p2 += __shfl_xor(p2, off);
    }
    float m = fmaxf(p1, p2);
    float e1 = __expf(p1 - m), e2 = __expf(p2 - m);
    float inv = 1.f / (e1 + e2);
    a0v[a] = e1 * inv;
    a1v[a] = e2 * inv;
  }

  // epilogue: Z = a0*ZP + a1*ZN -> Zf
#pragma unroll
  for (int a = 0; a < 4; ++a) {
    int node = node0 + ty + 16 * a;
    if (node < NN) {
      float* op = Zf + (size_t)node * 64;
#pragma unroll
      for (int b = 0; b < 4; ++b) {
        int col = tx + 16 * b;
        int base = (ty + 16 * a) * TS + col;
        op[col] = a0v[a] * TB[base] + a1v[a] * TA[base];
      }
    }
  }
}

// 16-lane sub-group per batch element; block handles 16; grid = ceil(B/16)
__global__ __launch_bounds__(256) void k_score(const float* __restrict__ Z,
                                               const int* __restrict__ u,
                                               const int* __restrict__ v,
                                               const int* __restrict__ n,
                                               const float* __restrict__ w,
                                               float* __restrict__ out, int B, int K) {
  __shared__ float xbuf[16][65];   // K <= 64
  __shared__ float part[16];
  int t = threadIdx.x;
  int wv = t >> 6, lane = t & 63;
  int sg = lane >> 4, sl = lane & 15;
  int bloc = wv * 4 + sg;
  int b = blockIdx.x * 16 + bloc;
  float lossb = 0.f;
  if (b < B) {
    int uid = u[b], vid = v[b];
    float4 u4 = *(const float4*)&Z[(size_t)uid * 64 + sl * 4];
    float4 v4 = *(const float4*)&Z[(size_t)vid * 64 + sl * 4];
    float p = u4.x * v4.x + u4.y * v4.y + u4.z * v4.z + u4.w * v4.w;
#pragma unroll
    for (int off = 8; off; off >>= 1) p += __shfl_xor(p, off);
    float wb = w[b];
    float sgn = (wb > 0.f) ? 1.f : ((wb < 0.f) ? -1.f : 0.f);
    float sp = sgn * p;
    float regl = u4.x * u4.x + u4.y * u4.y + u4.z * u4.z + u4.w * u4.w
               + v4.x * v4.x + v4.y * v4.y + v4.z * v4.z + v4.w * v4.w;
    const int* nb_ = n + (size_t)b * K;
    for (int k = 0; k < K; ++k) {
      int nid = nb_[k];
      float4 n4 = *(const float4*)&Z[(size_t)nid * 64 + sl * 4];
      float d = u4.x * n4.x + u4.y * n4.y + u4.z * n4.z + u4.w * n4.w;
      regl += n4.x * n4.x + n4.y * n4.y + n4.z * n4.z + n4.w * n4.w;
#pragma unroll
      for (int off = 8; off; off >>= 1) d += __shfl_xor(d, off);
      if (sl == 0) xbuf[bloc][k] = sp - d;
    }
#pragma unroll
    for (int off = 8; off; off >>= 1) regl += __shfl_xor(regl, off);
    float sb = 0.f;
    for (int k = sl; k < K; k += 16) {
      float x = xbuf[bloc][k];
      sb += fminf(x, 0.f) - log1pf(expf(-fabsf(x)));
    }
#pragma unroll
    for (int off = 8; off; off >>= 1) sb += __shfl_xor(sb, off);
    lossb = -sb + 1e-4f * regl;
  }
  if (sl == 0) part[bloc] = (b < B) ? lossb : 0.f;
  __syncthreads();
  if (t == 0) {
    float s = 0.f;
#pragma unroll
    for (int i = 0; i < 16; ++i) s += part[i];
    unsafeAtomicAdd(out, s);
  }
}

extern "C" void kernel_launch(void* const* d_in, const int* in_sizes, int n_in,
                              void* d_out, int out_size, void* d_ws, size_t ws_size,
                              hipStream_t stream) {
  const float* E  = (const float*)d_in[0];
  const float* E2 = (const float*)d_in[1];
  const float* Wm = (const float*)d_in[2];
  const float* bm = (const float*)d_in[3];
  const float* AW = (const float*)d_in[4];
  const float* ab = (const float*)d_in[5];
  const float* qw = (const float*)d_in[6];
  const int*   ei = (const int*)d_in[7];
  const int*   u  = (const int*)d_in[8];
  const int*   v  = (const int*)d_in[9];
  const int*   nn = (const int*)d_in[10];
  const float* w  = (const float*)d_in[11];

  const int NN = in_sizes[0] / 64;        // 150000
  const int NE = in_sizes[7] / 2;         // 3200000
  const int B  = in_sizes[8];             // 16384
  const int K  = in_sizes[10] / B;        // 40

  const int* src = ei;
  const int* dst = ei + NE;

  // workspace layout (float units)
  float*  ws     = (float*)d_ws;
  float*  dinv   = ws;                        // NN
  float*  Zf     = dinv + NN;                 // NN*64
  ushort* Eh     = (ushort*)(Zf + (size_t)NN * 64);  // NN*64 ushorts
  ushort* b1h    = Eh + (size_t)NN * 64;
  ushort* b2h    = b1h + (size_t)NN * 64;
  int*    deg_i  = (int*)(b2h + (size_t)NN * 64);    // NN ints
  int*    rowptr = deg_i + NN;                // NN+1 ints
  int*    bsum   = rowptr + NN + 1;           // <=1024 ints
  int*    csrc   = bsum + 1024;               // NE ints
  int*    rank   = csrc + NE;                 // NE ints
  float*  outf   = (float*)d_out;

  const int nb = (NN + 255) / 256;            // scan blocks (<=1024)

  hipMemsetAsync(deg_i, 0, (size_t)NN * sizeof(int), stream);
  hipMemsetAsync(outf, 0, sizeof(float), stream);

  k_half<<<(NN * 8 + 255) / 256, 256, 0, stream>>>(E, Eh, NN * 8);
  k_count<<<(NE + 255) / 256, 256, 0, stream>>>(dst, deg_i, rank, NE);
  k_scan1<<<nb, 256, 0, stream>>>(deg_i, bsum, NN);
  k_scan2<<<1, 1024, 0, stream>>>(bsum, nb);
  k_scan3<<<nb, 256, 0, stream>>>(deg_i, bsum, rowptr, NN);
  k_dinv<<<(NN + 255) / 256, 256, 0, stream>>>(deg_i, dinv, NN);
  k_scatter<<<(NE + 255) / 256, 256, 0, stream>>>(src, dst, rowptr, rank, csrc, NE);

  int gatherBlocks = ((size_t)NN * 16 + 255) / 256;   // 16 lanes per node
  k_gather<<<gatherBlocks, 256, 0, stream>>>(Eh, rowptr, csrc, dinv, b1h, NN);
  k_gather<<<gatherBlocks, 256, 0, stream>>>(b1h, rowptr, csrc, dinv, b2h, NN);

  int nodeTiles = (NN + 63) / 64;
  k_node<<<nodeTiles, 256, 0, stream>>>(E, E2, Wm, bm, AW, ab, qw, b1h, b2h, Zf, NN);

  k_score<<<(B + 15) / 16, 256, 0, stream>>>(Zf, u, v, nn, w, outf, B, K);
}

// Round 13
// 436.342 us; speedup vs baseline: 1.7618x; 1.1938x over previous
//
#include <hip/hip_runtime.h>
#include <math.h>

// ---------------------------------------------------------------------------
// SiReN loss on MI355X — round 13: LDS-privatized bucket-sort CSR build.
// Global atomics 3.2M -> ~75K (memory-side atomic unit was the 140us floor).
// k_bucket: chunk -> LDS hist(293 buckets) -> reserve -> scatter (dl,src) 8B.
// k_small : bucket base scan.
// k_fine  : per-bucket LDS count+scan -> rowptr/dinv/csrc, all LDS atomics.
// ---------------------------------------------------------------------------

typedef unsigned int uint;
typedef unsigned short ushort;
typedef unsigned long long ull;

#define BK_SHIFT 9
#define BK_SIZE 512
#define CAP 20480      // max bucket ~16.4K (+32 sigma margin)

__device__ inline float b2f(ushort u) { return __uint_as_float(((uint)u) << 16); }
__device__ inline ushort f2b(float f) {
  uint u = __float_as_uint(f);
  return (ushort)((u + 0x7fffu + ((u >> 16) & 1u)) >> 16);
}
__device__ inline uint pack2(float lo, float hi) {
  return (uint)f2b(lo) | ((uint)f2b(hi) << 16);
}

// f32 -> bf16 converter: thread handles 8 elems
__global__ void k_half(const float* __restrict__ x, ushort* __restrict__ out, int n8) {
  int i = blockIdx.x * blockDim.x + threadIdx.x;
  if (i >= n8) return;
  const float4* p = (const float4*)(x + (size_t)i * 8);
  float4 a = p[0], b = p[1];
  uint4 o;
  o.x = pack2(a.x, a.y); o.y = pack2(a.z, a.w);
  o.z = pack2(b.x, b.y); o.w = pack2(b.z, b.w);
  ((uint4*)out)[i] = o;
}

// bucket-partition edges: LDS histogram + one global atomic per (block,bucket)
__global__ __launch_bounds__(256) void k_bucket(const int* __restrict__ src,
                                                const int* __restrict__ dst,
                                                int* __restrict__ gcursor,
                                                ull* __restrict__ ebuf,
                                                int NE, int nbkt, int chunk) {
  __shared__ int hist[1024];
  __shared__ int curb[1024];
  int tid = threadIdx.x;
  for (int g = tid; g < nbkt; g += 256) hist[g] = 0;
  __syncthreads();
  int lo = blockIdx.x * chunk;
  int hi = min(lo + chunk, NE);
  for (int e = lo + tid; e < hi; e += 256)
    atomicAdd(&hist[dst[e] >> BK_SHIFT], 1);
  __syncthreads();
  for (int g = tid; g < nbkt; g += 256) {
    int c = hist[g];
    curb[g] = (c > 0) ? atomicAdd(&gcursor[g], c) : 0;
  }
  __syncthreads();
  for (int e = lo + tid; e < hi; e += 256) {
    int d = dst[e];
    int g = d >> BK_SHIFT;
    int pos = atomicAdd(&curb[g], 1);
    if (pos < CAP)
      ebuf[(size_t)g * CAP + pos] = ((ull)(uint)(d & (BK_SIZE - 1)) << 32) | (uint)src[e];
  }
}

// exclusive scan of bucket totals (nbkt <= 1024), single block
__global__ void k_small(const int* __restrict__ gcursor, int* __restrict__ bktbase,
                        int nbkt) {
  __shared__ int sm[1024];
  int t = threadIdx.x;
  int v = (t < nbkt) ? gcursor[t] : 0;
  sm[t] = v;
  __syncthreads();
  for (int off = 1; off < 1024; off <<= 1) {
    int a = (t >= off) ? sm[t - off] : 0;
    __syncthreads();
    sm[t] += a;
    __syncthreads();
  }
  if (t < nbkt) bktbase[t] = sm[t] - v;
  if (t == 0) bktbase[nbkt] = sm[1023];
}

// per-bucket: LDS count -> LDS scan -> rowptr+dinv, then place csrc
__global__ __launch_bounds__(256) void k_fine(const ull* __restrict__ ebuf,
                                              const int* __restrict__ gcursor,
                                              const int* __restrict__ bktbase,
                                              int* __restrict__ rowptr,
                                              float* __restrict__ dinv,
                                              int* __restrict__ csrc,
                                              int NN, int nbkt) {
  __shared__ int degl[BK_SIZE];
  __shared__ int lpl[BK_SIZE];
  __shared__ int ssum[256];
  int g = blockIdx.x;
  int tid = threadIdx.x;
  int cnt = gcursor[g];
  int base = bktbase[g];
  size_t ebase = (size_t)g * CAP;
  for (int j = tid; j < BK_SIZE; j += 256) degl[j] = 0;
  __syncthreads();
  for (int i = tid; i < cnt; i += 256)
    atomicAdd(&degl[(int)(ebuf[ebase + i] >> 32)], 1);
  __syncthreads();
  // exclusive scan of degl[512]: thread owns 2 elems
  int d0 = degl[2 * tid], d1 = degl[2 * tid + 1];
  int s = d0 + d1;
  ssum[tid] = s;
  __syncthreads();
  for (int off = 1; off < 256; off <<= 1) {
    int a = (tid >= off) ? ssum[tid - off] : 0;
    __syncthreads();
    ssum[tid] += a;
    __syncthreads();
  }
  int excl = ssum[tid] - s;
  lpl[2 * tid] = excl;
  lpl[2 * tid + 1] = excl + d0;
  int node0 = g * BK_SIZE;
  int n0 = node0 + 2 * tid, n1 = n0 + 1;
  if (n0 < NN) {
    rowptr[n0] = base + excl;
    dinv[n0] = (d0 > 0) ? rsqrtf((float)d0) : 0.f;
  }
  if (n1 < NN) {
    rowptr[n1] = base + excl + d0;
    dinv[n1] = (d1 > 0) ? rsqrtf((float)d1) : 0.f;
  }
  if (g == nbkt - 1 && tid == 255) rowptr[NN] = base + excl + d0 + d1;
  __syncthreads();
  for (int i = tid; i < cnt; i += 256) {
    ull e = ebuf[ebase + i];
    int dl = (int)(e >> 32);
    int r = atomicAdd(&lpl[dl], 1);
    csrc[base + r] = (int)(uint)e;
  }
}

// 16-lane sub-group per node; bf16 rows (8B/lane), f32 accumulate, 4x unroll
__global__ __launch_bounds__(256) void k_gather(const ushort* __restrict__ x,
                                                const int* __restrict__ rowptr,
                                                const int* __restrict__ csrc,
                                                const float* __restrict__ dinv,
                                                ushort* __restrict__ out, int NN) {
  int gid = blockIdx.x * blockDim.x + threadIdx.x;
  int node = gid >> 4;
  if (node >= NN) return;
  int sl = gid & 15;
  int beg = rowptr[node], end = rowptr[node + 1];
  float dn = dinv[node];
  float a0 = 0.f, a1 = 0.f, a2 = 0.f, a3 = 0.f;
  int i = beg;
  for (; i + 3 < end; i += 4) {
    int s0 = csrc[i], s1 = csrc[i + 1], s2 = csrc[i + 2], s3 = csrc[i + 3];
    float n0 = dinv[s0], n1 = dinv[s1], n2 = dinv[s2], n3 = dinv[s3];
    ushort4 r0 = *(const ushort4*)&x[(size_t)s0 * 64 + sl * 4];
    ushort4 r1 = *(const ushort4*)&x[(size_t)s1 * 64 + sl * 4];
    ushort4 r2 = *(const ushort4*)&x[(size_t)s2 * 64 + sl * 4];
    ushort4 r3 = *(const ushort4*)&x[(size_t)s3 * 64 + sl * 4];
    a0 += n0 * b2f(r0.x); a1 += n0 * b2f(r0.y); a2 += n0 * b2f(r0.z); a3 += n0 * b2f(r0.w);
    a0 += n1 * b2f(r1.x); a1 += n1 * b2f(r1.y); a2 += n1 * b2f(r1.z); a3 += n1 * b2f(r1.w);
    a0 += n2 * b2f(r2.x); a1 += n2 * b2f(r2.y); a2 += n2 * b2f(r2.z); a3 += n2 * b2f(r2.w);
    a0 += n3 * b2f(r3.x); a1 += n3 * b2f(r3.y); a2 += n3 * b2f(r3.z); a3 += n3 * b2f(r3.w);
  }
  for (; i < end; ++i) {
    int s0 = csrc[i];
    float n0 = dinv[s0];
    ushort4 r0 = *(const ushort4*)&x[(size_t)s0 * 64 + sl * 4];
    a0 += n0 * b2f(r0.x); a1 += n0 * b2f(r0.y); a2 += n0 * b2f(r0.z); a3 += n0 * b2f(r0.w);
  }
  ushort4 o;
  o.x = f2b(a0 * dn); o.y = f2b(a1 * dn); o.z = f2b(a2 * dn); o.w = f2b(a3 * dn);
  *(ushort4*)&out[(size_t)node * 64 + sl * 4] = o;
}

// ---------------------------------------------------------------------------
// k_node: 64-node tile; 4x4 register tile; LDS weight buffer (col-major,
// stride 68, float4-staged, re-staged W0->W1->AW); b128 k-chunked reads.
// ---------------------------------------------------------------------------
#define TS 68

__device__ inline float fast_tanh(float x) {
  float t = __expf(fminf(fmaxf(2.f * x, -30.f), 30.f));
  return (t - 1.f) / (t + 1.f);
}

__device__ inline void dot4(float acc[4][4], const float4 xv[4], const float4 wv[4]) {
#pragma unroll
  for (int a = 0; a < 4; ++a)
#pragma unroll
    for (int b = 0; b < 4; ++b) {
      acc[a][b] += xv[a].x * wv[b].x;
      acc[a][b] += xv[a].y * wv[b].y;
      acc[a][b] += xv[a].z * wv[b].z;
      acc[a][b] += xv[a].w * wv[b].w;
    }
}

__global__ __launch_bounds__(256, 4) void k_node(const float* __restrict__ E,
                                                 const float* __restrict__ E2,
                                                 const float* __restrict__ Wm,
                                                 const float* __restrict__ bm,
                                                 const float* __restrict__ AW,
                                                 const float* __restrict__ ab,
                                                 const float* __restrict__ qw,
                                                 const ushort* __restrict__ b1h,
                                                 const ushort* __restrict__ b2h,
                                                 float* __restrict__ Zf,
                                                 int NN) {
  __shared__ __align__(16) float Wl[64 * TS];
  __shared__ __align__(16) float TA[64 * TS];
  __shared__ __align__(16) float TB[64 * TS];
  __shared__ float b0s[64], b1s[64], abs_[64], qs[64];

  int tid = threadIdx.x;
  int tx = tid & 15, ty = tid >> 4;
  int lrow = tid >> 2;
  int lcol = (tid & 3) * 16;
  int node0 = blockIdx.x * 64;
  int snode = node0 + lrow;
  bool sok = snode < NN;
  const float4 z4 = make_float4(0.f, 0.f, 0.f, 0.f);

  for (int idx = tid; idx < 1024; idx += 256) {
    int col = idx >> 4, kc = idx & 15;
    *(float4*)&Wl[col * TS + kc * 4] = *(const float4*)&Wm[col * 64 + kc * 4];
  }
  if (tid < 64) { b0s[tid] = bm[tid]; b1s[tid] = bm[64 + tid]; abs_[tid] = ab[tid]; qs[tid] = qw[tid]; }
  {
    const float* sp = E2 + (size_t)snode * 64 + lcol;
#pragma unroll
    for (int c = 0; c < 4; ++c)
      *(float4*)&TA[lrow * TS + lcol + 4 * c] = sok ? *(const float4*)(sp + 4 * c) : z4;
  }
  __syncthreads();

  float acc[4][4];

  // GEMM1: acc = E2 @ W0^T + b0
#pragma unroll
  for (int a = 0; a < 4; ++a)
#pragma unroll
    for (int b = 0; b < 4; ++b) acc[a][b] = b0s[tx + 16 * b];
#pragma unroll 2
  for (int kc = 0; kc < 16; ++kc) {
    float4 xv[4], wv[4];
#pragma unroll
    for (int a = 0; a < 4; ++a) xv[a] = *(const float4*)&TA[(ty + 16 * a) * TS + kc * 4];
#pragma unroll
    for (int b = 0; b < 4; ++b) wv[b] = *(const float4*)&Wl[(tx + 16 * b) * TS + kc * 4];
    dot4(acc, xv, wv);
  }
  __syncthreads();

  for (int idx = tid; idx < 1024; idx += 256) {
    int col = idx >> 4, kc = idx & 15;
    *(float4*)&Wl[col * TS + kc * 4] = *(const float4*)&Wm[4096 + col * 64 + kc * 4];
  }
#pragma unroll
  for (int a = 0; a < 4; ++a)
#pragma unroll
    for (int b = 0; b < 4; ++b)
      TB[(ty + 16 * a) * TS + tx + 16 * b] = fmaxf(acc[a][b], 0.f);
  __syncthreads();

  // GEMM2: acc = H @ W1^T + b1
#pragma unroll
  for (int a = 0; a < 4; ++a)
#pragma unroll
    for (int b = 0; b < 4; ++b) acc[a][b] = b1s[tx + 16 * b];
#pragma unroll 2
  for (int kc = 0; kc < 16; ++kc) {
    float4 xv[4], wv[4];
#pragma unroll
    for (int a = 0; a < 4; ++a) xv[a] = *(const float4*)&TB[(ty + 16 * a) * TS + kc * 4];
#pragma unroll
    for (int b = 0; b < 4; ++b) wv[b] = *(const float4*)&Wl[(tx + 16 * b) * TS + kc * 4];
    dot4(acc, xv, wv);
  }
  __syncthreads();

  for (int idx = tid; idx < 1024; idx += 256) {
    int col = idx >> 4, kc = idx & 15;
    *(float4*)&Wl[col * TS + kc * 4] = *(const float4*)&AW[col * 64 + kc * 4];
  }
#pragma unroll
  for (int a = 0; a < 4; ++a)
#pragma unroll
    for (int b = 0; b < 4; ++b)
      TA[(ty + 16 * a) * TS + tx + 16 * b] = fmaxf(acc[a][b], 0.f);
  {
    const float* pe = E + (size_t)snode * 64 + lcol;
    const ushort* p1 = b1h + (size_t)snode * 64 + lcol;
    const ushort* p2 = b2h + (size_t)snode * 64 + lcol;
#pragma unroll
    for (int c = 0; c < 4; ++c) {
      float4 e4 = sok ? *(const float4*)(pe + 4 * c) : z4;
      ushort4 q1 = sok ? *(const ushort4*)(p1 + 4 * c) : make_ushort4(0, 0, 0, 0);
      ushort4 q2 = sok ? *(const ushort4*)(p2 + 4 * c) : make_ushort4(0, 0, 0, 0);
      float4 o;
      o.x = (e4.x + b2f(q1.x) + b2f(q2.x)) * (1.f / 3.f);
      o.y = (e4.y + b2f(q1.y) + b2f(q2.y)) * (1.f / 3.f);
      o.z = (e4.z + b2f(q1.z) + b2f(q2.z)) * (1.f / 3.f);
      o.w = (e4.w + b2f(q1.w) + b2f(q2.w)) * (1.f / 3.f);
      *(float4*)&TB[lrow * TS + lcol + 4 * c] = o;
    }
  }
  __syncthreads();

  float ac1[4][4], ac2[4][4];
#pragma unroll
  for (int a = 0; a < 4; ++a)
#pragma unroll
    for (int b = 0; b < 4; ++b) { ac1[a][b] = abs_[tx + 16 * b]; ac2[a][b] = ac1[a][b]; }
#pragma unroll 2
  for (int kc = 0; kc < 16; ++kc) {
    float4 zp[4], zn[4], wv[4];
#pragma unroll
    for (int a = 0; a < 4; ++a) {
      zp[a] = *(const float4*)&TB[(ty + 16 * a) * TS + kc * 4];
      zn[a] = *(const float4*)&TA[(ty + 16 * a) * TS + kc * 4];
    }
#pragma unroll
    for (int b = 0; b < 4; ++b) wv[b] = *(const float4*)&Wl[(tx + 16 * b) * TS + kc * 4];
    dot4(ac1, zp, wv);
    dot4(ac2, zn, wv);
  }

  float a0v[4], a1v[4];
#pragma unroll
  for (int a = 0; a < 4; ++a) {
    float p1 = 0.f, p2 = 0.f;
#pragma unroll
    for (int b = 0; b < 4; ++b) {
      float q = qs[tx + 16 * b];
      p1 += fast_tanh(ac1[a][b]) * q;
      p2 += fast_tanh(ac2[a][b]) * q;
    }
#pragma unroll
    for (int off = 8; off; off >>= 1) {
      p1 += __shfl_xor(p1, off);
      p2 += __shfl_xor(p2, off);
    }
    float m = fmaxf(p1, p2);
    float e1 = __expf(p1 - m), e2 = __expf(p2 - m);
    float inv = 1.f / (e1 + e2);
    a0v[a] = e1 * inv;
    a1v[a] = e2 * inv;
  }

#pragma unroll
  for (int a = 0; a < 4; ++a) {
    int node = node0 + ty + 16 * a;
    if (node < NN) {
      float* op = Zf + (size_t)node * 64;
#pragma unroll
      for (int b = 0; b < 4; ++b) {
        int col = tx + 16 * b;
        int base = (ty + 16 * a) * TS + col;
        op[col] = a0v[a] * TB[base] + a1v[a] * TA[base];
      }
    }
  }
}

// 16-lane sub-group per batch element; block handles 16; grid = ceil(B/16)
__global__ __launch_bounds__(256) void k_score(const float* __restrict__ Z,
                                               const int* __restrict__ u,
                                               const int* __restrict__ v,
                                               const int* __restrict__ n,
                                               const float* __restrict__ w,
                                               float* __restrict__ out, int B, int K) {
  __shared__ float xbuf[16][65];
  __shared__ float part[16];
  int t = threadIdx.x;
  int wv = t >> 6, lane = t & 63;
  int sg = lane >> 4, sl = lane & 15;
  int bloc = wv * 4 + sg;
  int b = blockIdx.x * 16 + bloc;
  float lossb = 0.f;
  if (b < B) {
    int uid = u[b], vid = v[b];
    float4 u4 = *(const float4*)&Z[(size_t)uid * 64 + sl * 4];
    float4 v4 = *(const float4*)&Z[(size_t)vid * 64 + sl * 4];
    float p = u4.x * v4.x + u4.y * v4.y + u4.z * v4.z + u4.w * v4.w;
#pragma unroll
    for (int off = 8; off; off >>= 1) p += __shfl_xor(p, off);
    float wb = w[b];
    float sgn = (wb > 0.f) ? 1.f : ((wb < 0.f) ? -1.f : 0.f);
    float sp = sgn * p;
    float regl = u4.x * u4.x + u4.y * u4.y + u4.z * u4.z + u4.w * u4.w
               + v4.x * v4.x + v4.y * v4.y + v4.z * v4.z + v4.w * v4.w;
    const int* nb_ = n + (size_t)b * K;
    for (int k = 0; k < K; ++k) {
      int nid = nb_[k];
      float4 n4 = *(const float4*)&Z[(size_t)nid * 64 + sl * 4];
      float d = u4.x * n4.x + u4.y * n4.y + u4.z * n4.z + u4.w * n4.w;
      regl += n4.x * n4.x + n4.y * n4.y + n4.z * n4.z + n4.w * n4.w;
#pragma unroll
      for (int off = 8; off; off >>= 1) d += __shfl_xor(d, off);
      if (sl == 0) xbuf[bloc][k] = sp - d;
    }
#pragma unroll
    for (int off = 8; off; off >>= 1) regl += __shfl_xor(regl, off);
    float sb = 0.f;
    for (int k = sl; k < K; k += 16) {
      float x = xbuf[bloc][k];
      sb += fminf(x, 0.f) - log1pf(expf(-fabsf(x)));
    }
#pragma unroll
    for (int off = 8; off; off >>= 1) sb += __shfl_xor(sb, off);
    lossb = -sb + 1e-4f * regl;
  }
  if (sl == 0) part[bloc] = (b < B) ? lossb : 0.f;
  __syncthreads();
  if (t == 0) {
    float s = 0.f;
#pragma unroll
    for (int i = 0; i < 16; ++i) s += part[i];
    unsafeAtomicAdd(out, s);
  }
}

extern "C" void kernel_launch(void* const* d_in, const int* in_sizes, int n_in,
                              void* d_out, int out_size, void* d_ws, size_t ws_size,
                              hipStream_t stream) {
  const float* E  = (const float*)d_in[0];
  const float* E2 = (const float*)d_in[1];
  const float* Wm = (const float*)d_in[2];
  const float* bm = (const float*)d_in[3];
  const float* AW = (const float*)d_in[4];
  const float* ab = (const float*)d_in[5];
  const float* qw = (const float*)d_in[6];
  const int*   ei = (const int*)d_in[7];
  const int*   u  = (const int*)d_in[8];
  const int*   v  = (const int*)d_in[9];
  const int*   nn = (const int*)d_in[10];
  const float* w  = (const float*)d_in[11];

  const int NN = in_sizes[0] / 64;        // 150000
  const int NE = in_sizes[7] / 2;         // 3200000
  const int B  = in_sizes[8];             // 16384
  const int K  = in_sizes[10] / B;        // 40
  const int NBKT = (NN + BK_SIZE - 1) / BK_SIZE;   // 293

  const int* src = ei;
  const int* dst = ei + NE;

  // workspace layout
  float*  ws      = (float*)d_ws;
  float*  dinv    = ws;                               // NN floats
  ushort* Eh      = (ushort*)(dinv + NN);             // NN*64 ushorts
  ushort* b1h     = Eh + (size_t)NN * 64;
  ushort* b2h     = b1h + (size_t)NN * 64;
  int*    rowptr  = (int*)(b2h + (size_t)NN * 64);    // NN+1 ints
  int*    csrc    = rowptr + NN + 1;                  // NE ints
  int*    gcursor = csrc + NE;                        // NBKT ints
  int*    bktbase = gcursor + NBKT;                   // NBKT+1 ints
  ull*    ebuf    = (ull*)(((uintptr_t)(bktbase + NBKT + 1) + 15) & ~(uintptr_t)15);
  float*  Zf      = (float*)ebuf;                     // aliases ebuf (dead after k_fine)
  float*  outf    = (float*)d_out;

  hipMemsetAsync(gcursor, 0, (size_t)NBKT * sizeof(int), stream);
  hipMemsetAsync(outf, 0, sizeof(float), stream);

  k_half<<<(NN * 8 + 255) / 256, 256, 0, stream>>>(E, Eh, NN * 8);

  int chunk = (NE + 255) / 256;
  k_bucket<<<256, 256, 0, stream>>>(src, dst, gcursor, ebuf, NE, NBKT, chunk);
  k_small<<<1, 1024, 0, stream>>>(gcursor, bktbase, NBKT);
  k_fine<<<NBKT, 256, 0, stream>>>(ebuf, gcursor, bktbase, rowptr, dinv, csrc, NN, NBKT);

  int gatherBlocks = ((size_t)NN * 16 + 255) / 256;   // 16 lanes per node
  k_gather<<<gatherBlocks, 256, 0, stream>>>(Eh, rowptr, csrc, dinv, b1h, NN);
  k_gather<<<gatherBlocks, 256, 0, stream>>>(b1h, rowptr, csrc, dinv, b2h, NN);

  int nodeTiles = (NN + 63) / 64;
  k_node<<<nodeTiles, 256, 0, stream>>>(E, E2, Wm, bm, AW, ab, qw, b1h, b2h, Zf, NN);

  k_score<<<(B + 15) / 16, 256, 0, stream>>>(Zf, u, v, nn, w, outf, B, K);
}

// Round 14
// 387.388 us; speedup vs baseline: 1.9844x; 1.1264x over previous
//
#include <hip/hip_runtime.h>
#include <math.h>

// ---------------------------------------------------------------------------
// SiReN loss on MI355X — round 14: k_node on MFMA (bf16 matrix cores).
// 4 waves/block, wave = 16 rows x 64 cols (4 C-tiles, 2 mfma each, K=64).
// GEMM1 A from E2 (f32->bf16 in-reg), GEMM2/attn A from bf16 LDS [64][72].
// B-frags straight from row-major bf16 weights (Wmh/AWh, pre-converted).
// ---------------------------------------------------------------------------

typedef unsigned int uint;
typedef unsigned short ushort;
typedef unsigned long long ull;
typedef __attribute__((ext_vector_type(8))) short short8v;
typedef __attribute__((ext_vector_type(4))) float float4v;

#define BK_SHIFT 9
#define BK_SIZE 512
#define CAP 20480

__device__ inline float b2f(ushort u) { return __uint_as_float(((uint)u) << 16); }
__device__ inline ushort f2b(float f) {
  uint u = __float_as_uint(f);
  return (ushort)((u + 0x7fffu + ((u >> 16) & 1u)) >> 16);
}
__device__ inline uint pack2(float lo, float hi) {
  return (uint)f2b(lo) | ((uint)f2b(hi) << 16);
}

// f32 -> bf16 converter: thread handles 8 elems
__global__ void k_half(const float* __restrict__ x, ushort* __restrict__ out, int n8) {
  int i = blockIdx.x * blockDim.x + threadIdx.x;
  if (i >= n8) return;
  const float4* p = (const float4*)(x + (size_t)i * 8);
  float4 a = p[0], b = p[1];
  uint4 o;
  o.x = pack2(a.x, a.y); o.y = pack2(a.z, a.w);
  o.z = pack2(b.x, b.y); o.w = pack2(b.z, b.w);
  ((uint4*)out)[i] = o;
}

// bucket-partition edges: LDS histogram + one global atomic per (block,bucket)
__global__ __launch_bounds__(256) void k_bucket(const int* __restrict__ src,
                                                const int* __restrict__ dst,
                                                int* __restrict__ gcursor,
                                                ull* __restrict__ ebuf,
                                                int NE, int nbkt, int chunk) {
  __shared__ int hist[1024];
  __shared__ int curb[1024];
  int tid = threadIdx.x;
  for (int g = tid; g < nbkt; g += 256) hist[g] = 0;
  __syncthreads();
  int lo = blockIdx.x * chunk;
  int hi = min(lo + chunk, NE);
  for (int e = lo + tid; e < hi; e += 256)
    atomicAdd(&hist[dst[e] >> BK_SHIFT], 1);
  __syncthreads();
  for (int g = tid; g < nbkt; g += 256) {
    int c = hist[g];
    curb[g] = (c > 0) ? atomicAdd(&gcursor[g], c) : 0;
  }
  __syncthreads();
  for (int e = lo + tid; e < hi; e += 256) {
    int d = dst[e];
    int g = d >> BK_SHIFT;
    int pos = atomicAdd(&curb[g], 1);
    if (pos < CAP)
      ebuf[(size_t)g * CAP + pos] = ((ull)(uint)(d & (BK_SIZE - 1)) << 32) | (uint)src[e];
  }
}

// exclusive scan of bucket totals (nbkt <= 1024), single block
__global__ void k_small(const int* __restrict__ gcursor, int* __restrict__ bktbase,
                        int nbkt) {
  __shared__ int sm[1024];
  int t = threadIdx.x;
  int v = (t < nbkt) ? gcursor[t] : 0;
  sm[t] = v;
  __syncthreads();
  for (int off = 1; off < 1024; off <<= 1) {
    int a = (t >= off) ? sm[t - off] : 0;
    __syncthreads();
    sm[t] += a;
    __syncthreads();
  }
  if (t < nbkt) bktbase[t] = sm[t] - v;
  if (t == 0) bktbase[nbkt] = sm[1023];
}

// per-bucket: LDS count -> LDS scan -> rowptr+dinv, then place csrc
__global__ __launch_bounds__(256) void k_fine(const ull* __restrict__ ebuf,
                                              const int* __restrict__ gcursor,
                                              const int* __restrict__ bktbase,
                                              int* __restrict__ rowptr,
                                              float* __restrict__ dinv,
                                              int* __restrict__ csrc,
                                              int NN, int nbkt) {
  __shared__ int degl[BK_SIZE];
  __shared__ int lpl[BK_SIZE];
  __shared__ int ssum[256];
  int g = blockIdx.x;
  int tid = threadIdx.x;
  int cnt = gcursor[g];
  int base = bktbase[g];
  size_t ebase = (size_t)g * CAP;
  for (int j = tid; j < BK_SIZE; j += 256) degl[j] = 0;
  __syncthreads();
  for (int i = tid; i < cnt; i += 256)
    atomicAdd(&degl[(int)(ebuf[ebase + i] >> 32)], 1);
  __syncthreads();
  int d0 = degl[2 * tid], d1 = degl[2 * tid + 1];
  int s = d0 + d1;
  ssum[tid] = s;
  __syncthreads();
  for (int off = 1; off < 256; off <<= 1) {
    int a = (tid >= off) ? ssum[tid - off] : 0;
    __syncthreads();
    ssum[tid] += a;
    __syncthreads();
  }
  int excl = ssum[tid] - s;
  lpl[2 * tid] = excl;
  lpl[2 * tid + 1] = excl + d0;
  int node0 = g * BK_SIZE;
  int n0 = node0 + 2 * tid, n1 = n0 + 1;
  if (n0 < NN) {
    rowptr[n0] = base + excl;
    dinv[n0] = (d0 > 0) ? rsqrtf((float)d0) : 0.f;
  }
  if (n1 < NN) {
    rowptr[n1] = base + excl + d0;
    dinv[n1] = (d1 > 0) ? rsqrtf((float)d1) : 0.f;
  }
  if (g == nbkt - 1 && tid == 255) rowptr[NN] = base + excl + d0 + d1;
  __syncthreads();
  for (int i = tid; i < cnt; i += 256) {
    ull e = ebuf[ebase + i];
    int dl = (int)(e >> 32);
    int r = atomicAdd(&lpl[dl], 1);
    csrc[base + r] = (int)(uint)e;
  }
}

// 16-lane sub-group per node; bf16 rows (8B/lane), f32 accumulate, 4x unroll
__global__ __launch_bounds__(256) void k_gather(const ushort* __restrict__ x,
                                                const int* __restrict__ rowptr,
                                                const int* __restrict__ csrc,
                                                const float* __restrict__ dinv,
                                                ushort* __restrict__ out, int NN) {
  int gid = blockIdx.x * blockDim.x + threadIdx.x;
  int node = gid >> 4;
  if (node >= NN) return;
  int sl = gid & 15;
  int beg = rowptr[node], end = rowptr[node + 1];
  float dn = dinv[node];
  float a0 = 0.f, a1 = 0.f, a2 = 0.f, a3 = 0.f;
  int i = beg;
  for (; i + 3 < end; i += 4) {
    int s0 = csrc[i], s1 = csrc[i + 1], s2 = csrc[i + 2], s3 = csrc[i + 3];
    float n0 = dinv[s0], n1 = dinv[s1], n2 = dinv[s2], n3 = dinv[s3];
    ushort4 r0 = *(const ushort4*)&x[(size_t)s0 * 64 + sl * 4];
    ushort4 r1 = *(const ushort4*)&x[(size_t)s1 * 64 + sl * 4];
    ushort4 r2 = *(const ushort4*)&x[(size_t)s2 * 64 + sl * 4];
    ushort4 r3 = *(const ushort4*)&x[(size_t)s3 * 64 + sl * 4];
    a0 += n0 * b2f(r0.x); a1 += n0 * b2f(r0.y); a2 += n0 * b2f(r0.z); a3 += n0 * b2f(r0.w);
    a0 += n1 * b2f(r1.x); a1 += n1 * b2f(r1.y); a2 += n1 * b2f(r1.z); a3 += n1 * b2f(r1.w);
    a0 += n2 * b2f(r2.x); a1 += n2 * b2f(r2.y); a2 += n2 * b2f(r2.z); a3 += n2 * b2f(r2.w);
    a0 += n3 * b2f(r3.x); a1 += n3 * b2f(r3.y); a2 += n3 * b2f(r3.z); a3 += n3 * b2f(r3.w);
  }
  for (; i < end; ++i) {
    int s0 = csrc[i];
    float n0 = dinv[s0];
    ushort4 r0 = *(const ushort4*)&x[(size_t)s0 * 64 + sl * 4];
    a0 += n0 * b2f(r0.x); a1 += n0 * b2f(r0.y); a2 += n0 * b2f(r0.z); a3 += n0 * b2f(r0.w);
  }
  ushort4 o;
  o.x = f2b(a0 * dn); o.y = f2b(a1 * dn); o.z = f2b(a2 * dn); o.w = f2b(a3 * dn);
  *(ushort4*)&out[(size_t)node * 64 + sl * 4] = o;
}

// ---------------------------------------------------------------------------
// k_node (MFMA): per 64-node tile.
//   H  = relu(E2 @ W0^T + b0)       GEMM1 (A: E2 f32->bf16 in-reg)
//   ZN = relu(H @ W1^T + b1)        GEMM2 (A: Hl LDS)
//   ZP = (E + b1h + b2h)/3 -> Pl
//   a1 = ZP@AW^T+ab, a2 = ZN@AW^T+ab (attn GEMMs)
//   softmax(tanh(.)@q) -> Z -> Zf
// ---------------------------------------------------------------------------
__device__ inline float fast_tanh(float x) {
  float t = __expf(fminf(fmaxf(2.f * x, -30.f), 30.f));
  return (t - 1.f) / (t + 1.f);
}

__device__ inline short8v cvt8(const float* p) {
  float4 f0 = *(const float4*)p;
  float4 f1 = *(const float4*)(p + 4);
  uint4 u;
  u.x = pack2(f0.x, f0.y); u.y = pack2(f0.z, f0.w);
  u.z = pack2(f1.x, f1.y); u.w = pack2(f1.z, f1.w);
  return *(short8v*)&u;
}

#define MFMA(a, b, c) __builtin_amdgcn_mfma_f32_16x16x32_bf16((a), (b), (c), 0, 0, 0)

__global__ __launch_bounds__(256, 2) void k_node(const float* __restrict__ E,
                                                 const float* __restrict__ E2,
                                                 const ushort* __restrict__ Wmh,
                                                 const float* __restrict__ bm,
                                                 const ushort* __restrict__ AWh,
                                                 const float* __restrict__ ab,
                                                 const float* __restrict__ qw,
                                                 const ushort* __restrict__ b1h,
                                                 const ushort* __restrict__ b2h,
                                                 float* __restrict__ Zf,
                                                 int NN) {
  __shared__ ushort Hl[64 * 72];   // H, then ZN (bf16, stride 72)
  __shared__ ushort Pl[64 * 72];   // ZP (bf16)
  int tid = threadIdx.x;
  int lane = tid & 63, wid = tid >> 6;
  int r15 = lane & 15, kg = lane >> 4;      // kg 0..3: k-slice 8*kg
  int node0 = blockIdx.x * 64;

  // ---- GEMM1: acc = E2 @ W0^T + b0 ----
  int arow = node0 + 16 * wid + r15;
  int arowc = min(arow, NN - 1);
  const float* e2p = E2 + (size_t)arowc * 64 + 8 * kg;
  short8v a0 = cvt8(e2p);
  short8v a1 = cvt8(e2p + 32);
  float4v acc[4];
#pragma unroll
  for (int b = 0; b < 4; ++b) {
    int col = r15 + 16 * b;
    short8v w0 = *(const short8v*)&Wmh[col * 64 + 8 * kg];
    short8v w1 = *(const short8v*)&Wmh[col * 64 + 32 + 8 * kg];
    float bias = bm[col];
    acc[b] = (float4v){bias, bias, bias, bias};
    acc[b] = MFMA(a0, w0, acc[b]);
    acc[b] = MFMA(a1, w1, acc[b]);
  }
  // write H = relu(acc) -> Hl  (C layout: col=lane&15, row=4*kg+rr)
#pragma unroll
  for (int b = 0; b < 4; ++b)
#pragma unroll
    for (int rr = 0; rr < 4; ++rr)
      Hl[(16 * wid + 4 * kg + rr) * 72 + 16 * b + r15] = f2b(fmaxf(acc[b][rr], 0.f));

  // stage ZP = (E + b1h + b2h)/3 -> Pl (bf16)
  {
    int row = tid >> 2;
    int c0 = (tid & 3) * 16;
    int node = node0 + row;
    uint outp[8];
    if (node < NN) {
      const float* pe = E + (size_t)node * 64 + c0;
      const ushort* p1 = b1h + (size_t)node * 64 + c0;
      const ushort* p2 = b2h + (size_t)node * 64 + c0;
#pragma unroll
      for (int c = 0; c < 4; ++c) {
        float4 e4 = ((const float4*)pe)[c];
        ushort4 q1 = ((const ushort4*)p1)[c];
        ushort4 q2 = ((const ushort4*)p2)[c];
        float z0 = (e4.x + b2f(q1.x) + b2f(q2.x)) * (1.f / 3.f);
        float z1 = (e4.y + b2f(q1.y) + b2f(q2.y)) * (1.f / 3.f);
        float z2 = (e4.z + b2f(q1.z) + b2f(q2.z)) * (1.f / 3.f);
        float z3 = (e4.w + b2f(q1.w) + b2f(q2.w)) * (1.f / 3.f);
        outp[2 * c] = pack2(z0, z1);
        outp[2 * c + 1] = pack2(z2, z3);
      }
    } else {
#pragma unroll
      for (int c = 0; c < 8; ++c) outp[c] = 0;
    }
    *(uint4*)&Pl[row * 72 + c0] = *(uint4*)&outp[0];
    *(uint4*)&Pl[row * 72 + c0 + 8] = *(uint4*)&outp[4];
  }
  __syncthreads();

  // ---- GEMM2: acc2 = H @ W1^T + b1 ----
  const ushort* hap = &Hl[(16 * wid + r15) * 72 + 8 * kg];
  short8v ha0 = *(const short8v*)hap;
  short8v ha1 = *(const short8v*)(hap + 32);
  float4v acc2[4];
#pragma unroll
  for (int b = 0; b < 4; ++b) {
    int col = r15 + 16 * b;
    short8v w0 = *(const short8v*)&Wmh[4096 + col * 64 + 8 * kg];
    short8v w1 = *(const short8v*)&Wmh[4096 + col * 64 + 32 + 8 * kg];
    float bias = bm[64 + col];
    acc2[b] = (float4v){bias, bias, bias, bias};
    acc2[b] = MFMA(ha0, w0, acc2[b]);
    acc2[b] = MFMA(ha1, w1, acc2[b]);
  }
  __syncthreads();   // all Hl (H) reads done
  // ZN = relu(acc2) -> Hl
#pragma unroll
  for (int b = 0; b < 4; ++b)
#pragma unroll
    for (int rr = 0; rr < 4; ++rr)
      Hl[(16 * wid + 4 * kg + rr) * 72 + 16 * b + r15] = f2b(fmaxf(acc2[b][rr], 0.f));
  __syncthreads();

  // ---- attention GEMMs ----
  const ushort* pap = &Pl[(16 * wid + r15) * 72 + 8 * kg];
  short8v pa0 = *(const short8v*)pap;
  short8v pa1 = *(const short8v*)(pap + 32);
  const ushort* nap = &Hl[(16 * wid + r15) * 72 + 8 * kg];
  short8v na0 = *(const short8v*)nap;
  short8v na1 = *(const short8v*)(nap + 32);
  float4v ac1[4], ac2[4];
#pragma unroll
  for (int b = 0; b < 4; ++b) {
    int col = r15 + 16 * b;
    short8v w0 = *(const short8v*)&AWh[col * 64 + 8 * kg];
    short8v w1 = *(const short8v*)&AWh[col * 64 + 32 + 8 * kg];
    float bias = ab[col];
    ac1[b] = (float4v){bias, bias, bias, bias};
    ac1[b] = MFMA(pa0, w0, ac1[b]);
    ac1[b] = MFMA(pa1, w1, ac1[b]);
    ac2[b] = (float4v){bias, bias, bias, bias};
    ac2[b] = MFMA(na0, w0, ac2[b]);
    ac2[b] = MFMA(na1, w1, ac2[b]);
  }

  // ---- epilogue: per-row softmax over {w_p, w_n}; Z -> Zf ----
  float qv[4];
#pragma unroll
  for (int b = 0; b < 4; ++b) qv[b] = qw[r15 + 16 * b];
#pragma unroll
  for (int rr = 0; rr < 4; ++rr) {
    float wp = 0.f, wn = 0.f;
#pragma unroll
    for (int b = 0; b < 4; ++b) {
      wp += fast_tanh(ac1[b][rr]) * qv[b];
      wn += fast_tanh(ac2[b][rr]) * qv[b];
    }
#pragma unroll
    for (int off = 8; off; off >>= 1) {
      wp += __shfl_xor(wp, off);
      wn += __shfl_xor(wn, off);
    }
    float m = fmaxf(wp, wn);
    float e1 = __expf(wp - m), e2 = __expf(wn - m);
    float inv = 1.f / (e1 + e2);
    float al0 = e1 * inv, al1 = e2 * inv;
    int row_l = 16 * wid + 4 * kg + rr;
    int node = node0 + row_l;
    if (node < NN) {
      float* op = Zf + (size_t)node * 64;
#pragma unroll
      for (int b = 0; b < 4; ++b) {
        int col = r15 + 16 * b;
        int li = row_l * 72 + col;
        op[col] = al0 * b2f(Pl[li]) + al1 * b2f(Hl[li]);
      }
    }
  }
}

// 16-lane sub-group per batch element; block handles 16; grid = ceil(B/16)
__global__ __launch_bounds__(256) void k_score(const float* __restrict__ Z,
                                               const int* __restrict__ u,
                                               const int* __restrict__ v,
                                               const int* __restrict__ n,
                                               const float* __restrict__ w,
                                               float* __restrict__ out, int B, int K) {
  __shared__ float xbuf[16][65];
  __shared__ float part[16];
  int t = threadIdx.x;
  int wv = t >> 6, lane = t & 63;
  int sg = lane >> 4, sl = lane & 15;
  int bloc = wv * 4 + sg;
  int b = blockIdx.x * 16 + bloc;
  float lossb = 0.f;
  if (b < B) {
    int uid = u[b], vid = v[b];
    float4 u4 = *(const float4*)&Z[(size_t)uid * 64 + sl * 4];
    float4 v4 = *(const float4*)&Z[(size_t)vid * 64 + sl * 4];
    float p = u4.x * v4.x + u4.y * v4.y + u4.z * v4.z + u4.w * v4.w;
#pragma unroll
    for (int off = 8; off; off >>= 1) p += __shfl_xor(p, off);
    float wb = w[b];
    float sgn = (wb > 0.f) ? 1.f : ((wb < 0.f) ? -1.f : 0.f);
    float sp = sgn * p;
    float regl = u4.x * u4.x + u4.y * u4.y + u4.z * u4.z + u4.w * u4.w
               + v4.x * v4.x + v4.y * v4.y + v4.z * v4.z + v4.w * v4.w;
    const int* nb_ = n + (size_t)b * K;
    for (int k = 0; k < K; ++k) {
      int nid = nb_[k];
      float4 n4 = *(const float4*)&Z[(size_t)nid * 64 + sl * 4];
      float d = u4.x * n4.x + u4.y * n4.y + u4.z * n4.z + u4.w * n4.w;
      regl += n4.x * n4.x + n4.y * n4.y + n4.z * n4.z + n4.w * n4.w;
#pragma unroll
      for (int off = 8; off; off >>= 1) d += __shfl_xor(d, off);
      if (sl == 0) xbuf[bloc][k] = sp - d;
    }
#pragma unroll
    for (int off = 8; off; off >>= 1) regl += __shfl_xor(regl, off);
    float sb = 0.f;
    for (int k = sl; k < K; k += 16) {
      float x = xbuf[bloc][k];
      sb += fminf(x, 0.f) - log1pf(expf(-fabsf(x)));
    }
#pragma unroll
    for (int off = 8; off; off >>= 1) sb += __shfl_xor(sb, off);
    lossb = -sb + 1e-4f * regl;
  }
  if (sl == 0) part[bloc] = (b < B) ? lossb : 0.f;
  __syncthreads();
  if (t == 0) {
    float s = 0.f;
#pragma unroll
    for (int i = 0; i < 16; ++i) s += part[i];
    unsafeAtomicAdd(out, s);
  }
}

extern "C" void kernel_launch(void* const* d_in, const int* in_sizes, int n_in,
                              void* d_out, int out_size, void* d_ws, size_t ws_size,
                              hipStream_t stream) {
  const float* E  = (const float*)d_in[0];
  const float* E2 = (const float*)d_in[1];
  const float* Wm = (const float*)d_in[2];
  const float* bm = (const float*)d_in[3];
  const float* AW = (const float*)d_in[4];
  const float* ab = (const float*)d_in[5];
  const float* qw = (const float*)d_in[6];
  const int*   ei = (const int*)d_in[7];
  const int*   u  = (const int*)d_in[8];
  const int*   v  = (const int*)d_in[9];
  const int*   nn = (const int*)d_in[10];
  const float* w  = (const float*)d_in[11];

  const int NN = in_sizes[0] / 64;        // 150000
  const int NE = in_sizes[7] / 2;         // 3200000
  const int B  = in_sizes[8];             // 16384
  const int K  = in_sizes[10] / B;        // 40
  const int NBKT = (NN + BK_SIZE - 1) / BK_SIZE;   // 293

  const int* src = ei;
  const int* dst = ei + NE;

  // workspace layout
  float*  ws      = (float*)d_ws;
  float*  dinv    = ws;                               // NN floats
  ushort* Eh      = (ushort*)(dinv + NN);             // NN*64 ushorts
  ushort* b1h     = Eh + (size_t)NN * 64;
  ushort* b2h     = b1h + (size_t)NN * 64;
  ushort* Wmh     = b2h + (size_t)NN * 64;            // 8192 ushorts
  ushort* AWh     = Wmh + 8192;                       // 4096 ushorts
  int*    rowptr  = (int*)(AWh + 4096);               // NN+1 ints
  int*    csrc    = rowptr + NN + 1;                  // NE ints
  int*    gcursor = csrc + NE;                        // NBKT ints
  int*    bktbase = gcursor + NBKT;                   // NBKT+1 ints
  ull*    ebuf    = (ull*)(((uintptr_t)(bktbase + NBKT + 1) + 15) & ~(uintptr_t)15);
  float*  Zf      = (float*)ebuf;                     // aliases ebuf (dead after k_fine)
  float*  outf    = (float*)d_out;

  hipMemsetAsync(gcursor, 0, (size_t)NBKT * sizeof(int), stream);
  hipMemsetAsync(outf, 0, sizeof(float), stream);

  k_half<<<(NN * 8 + 255) / 256, 256, 0, stream>>>(E, Eh, NN * 8);
  k_half<<<4, 256, 0, stream>>>(Wm, Wmh, 1024);
  k_half<<<2, 256, 0, stream>>>(AW, AWh, 512);

  int chunk = (NE + 255) / 256;
  k_bucket<<<256, 256, 0, stream>>>(src, dst, gcursor, ebuf, NE, NBKT, chunk);
  k_small<<<1, 1024, 0, stream>>>(gcursor, bktbase, NBKT);
  k_fine<<<NBKT, 256, 0, stream>>>(ebuf, gcursor, bktbase, rowptr, dinv, csrc, NN, NBKT);

  int gatherBlocks = ((size_t)NN * 16 + 255) / 256;   // 16 lanes per node
  k_gather<<<gatherBlocks, 256, 0, stream>>>(Eh, rowptr, csrc, dinv, b1h, NN);
  k_gather<<<gatherBlocks, 256, 0, stream>>>(b1h, rowptr, csrc, dinv, b2h, NN);

  int nodeTiles = (NN + 63) / 64;
  k_node<<<nodeTiles, 256, 0, stream>>>(E, E2, Wmh, bm, AWh, ab, qw, b1h, b2h, Zf, NN);

  k_score<<<(B + 15) / 16, 256, 0, stream>>>(Zf, u, v, nn, w, outf, B, K);
}

// Round 15
// 312.079 us; speedup vs baseline: 2.4633x; 1.2413x over previous
//
#include <hip/hip_runtime.h>
#include <math.h>

// ---------------------------------------------------------------------------
// SiReN loss on MI355X — round 15: fp8(e4m3) propagation payload.
// Gather rows 128B(bf16) -> 64B(fp8): E->E8 once, b1q/b2q fp8; f32 accumulate.
// HW cvt builtins with __has_builtin guard + exact SW fallback (denormal-safe).
// k_node (MFMA bf16) unchanged except ZP stage decodes fp8; E stays f32.
// ---------------------------------------------------------------------------

typedef unsigned int uint;
typedef unsigned short ushort;
typedef unsigned char uchar;
typedef unsigned long long ull;
typedef __attribute__((ext_vector_type(8))) short short8v;
typedef __attribute__((ext_vector_type(4))) float float4v;
typedef __attribute__((ext_vector_type(2))) float float2v;

#define BK_SHIFT 9
#define BK_SIZE 512
#define CAP 20480

#if __has_builtin(__builtin_amdgcn_cvt_pk_f32_fp8) && __has_builtin(__builtin_amdgcn_cvt_pk_fp8_f32)
#define HW_FP8 1
#else
#define HW_FP8 0
#endif

__device__ inline float b2f(ushort u) { return __uint_as_float(((uint)u) << 16); }
__device__ inline ushort f2b(float f) {
  uint u = __float_as_uint(f);
  return (ushort)((u + 0x7fffu + ((u >> 16) & 1u)) >> 16);
}
__device__ inline uint pack2(float lo, float hi) {
  return (uint)f2b(lo) | ((uint)f2b(hi) << 16);
}

// ---- fp8 e4m3 helpers ----
__device__ inline float dec1(uint u) {
  uint e = (u >> 3) & 0xFu;
  uint m = u & 7u;
  uint s = (u & 0x80u) << 24;
  float norm = __uint_as_float(s | ((e + 120u) << 23) | (m << 20));
  float den = __uint_as_float(s | 0x3F800000u) * (float)(int)m * 0.001953125f; // m*2^-9
  return e ? norm : den;
}
__device__ inline uint enc1(float x) {
  uint s = (__float_as_uint(x) >> 24) & 0x80u;
  float ax = fminf(fabsf(x), 448.f);
  uint r;
  if (ax < 0.015625f) {
    r = (uint)(int)rintf(ax * 512.f);       // 8 naturally becomes e=1,m=0
  } else {
    uint b = __float_as_uint(ax);
    b += 0x7FFFFu + ((b >> 20) & 1u);       // RTNE at bit 20
    uint e = (b >> 23) - 120u;
    r = (e > 15u) ? 0x7Eu : ((e << 3) | ((b >> 20) & 7u));
  }
  return s | r;
}
__device__ inline float4 dec4(uint v) {
#if HW_FP8
  float2v lo = __builtin_amdgcn_cvt_pk_f32_fp8((int)v, false);
  float2v hi = __builtin_amdgcn_cvt_pk_f32_fp8((int)v, true);
  return make_float4(lo[0], lo[1], hi[0], hi[1]);
#else
  return make_float4(dec1(v & 0xFFu), dec1((v >> 8) & 0xFFu),
                     dec1((v >> 16) & 0xFFu), dec1(v >> 24));
#endif
}
__device__ inline uint enc4f(float a, float b, float c, float d) {
#if HW_FP8
  int v = 0;
  v = __builtin_amdgcn_cvt_pk_fp8_f32(a, b, v, false);
  v = __builtin_amdgcn_cvt_pk_fp8_f32(c, d, v, true);
  return (uint)v;
#else
  return enc1(a) | (enc1(b) << 8) | (enc1(c) << 16) | (enc1(d) << 24);
#endif
}

// f32 -> bf16 converter: thread handles 8 elems (weights)
__global__ void k_half(const float* __restrict__ x, ushort* __restrict__ out, int n8) {
  int i = blockIdx.x * blockDim.x + threadIdx.x;
  if (i >= n8) return;
  const float4* p = (const float4*)(x + (size_t)i * 8);
  float4 a = p[0], b = p[1];
  uint4 o;
  o.x = pack2(a.x, a.y); o.y = pack2(a.z, a.w);
  o.z = pack2(b.x, b.y); o.w = pack2(b.z, b.w);
  ((uint4*)out)[i] = o;
}

// f32 -> fp8 converter: thread handles 16 elems
__global__ void k_tofp8(const float* __restrict__ x, uint* __restrict__ out, int n16) {
  int i = blockIdx.x * blockDim.x + threadIdx.x;
  if (i >= n16) return;
  const float4* p = (const float4*)(x + (size_t)i * 16);
  float4 f0 = p[0], f1 = p[1], f2 = p[2], f3 = p[3];
  uint4 o;
  o.x = enc4f(f0.x, f0.y, f0.z, f0.w);
  o.y = enc4f(f1.x, f1.y, f1.z, f1.w);
  o.z = enc4f(f2.x, f2.y, f2.z, f2.w);
  o.w = enc4f(f3.x, f3.y, f3.z, f3.w);
  ((uint4*)out)[i] = o;
}

// bucket-partition edges: LDS histogram + one global atomic per (block,bucket)
__global__ __launch_bounds__(256) void k_bucket(const int* __restrict__ src,
                                                const int* __restrict__ dst,
                                                int* __restrict__ gcursor,
                                                ull* __restrict__ ebuf,
                                                int NE, int nbkt, int chunk) {
  __shared__ int hist[1024];
  __shared__ int curb[1024];
  int tid = threadIdx.x;
  for (int g = tid; g < nbkt; g += 256) hist[g] = 0;
  __syncthreads();
  int lo = blockIdx.x * chunk;
  int hi = min(lo + chunk, NE);
  for (int e = lo + tid; e < hi; e += 256)
    atomicAdd(&hist[dst[e] >> BK_SHIFT], 1);
  __syncthreads();
  for (int g = tid; g < nbkt; g += 256) {
    int c = hist[g];
    curb[g] = (c > 0) ? atomicAdd(&gcursor[g], c) : 0;
  }
  __syncthreads();
  for (int e = lo + tid; e < hi; e += 256) {
    int d = dst[e];
    int g = d >> BK_SHIFT;
    int pos = atomicAdd(&curb[g], 1);
    if (pos < CAP)
      ebuf[(size_t)g * CAP + pos] = ((ull)(uint)(d & (BK_SIZE - 1)) << 32) | (uint)src[e];
  }
}

// exclusive scan of bucket totals (nbkt <= 1024), single block
__global__ void k_small(const int* __restrict__ gcursor, int* __restrict__ bktbase,
                        int nbkt) {
  __shared__ int sm[1024];
  int t = threadIdx.x;
  int v = (t < nbkt) ? gcursor[t] : 0;
  sm[t] = v;
  __syncthreads();
  for (int off = 1; off < 1024; off <<= 1) {
    int a = (t >= off) ? sm[t - off] : 0;
    __syncthreads();
    sm[t] += a;
    __syncthreads();
  }
  if (t < nbkt) bktbase[t] = sm[t] - v;
  if (t == 0) bktbase[nbkt] = sm[1023];
}

// per-bucket: LDS count -> LDS scan -> rowptr+dinv, then place csrc
__global__ __launch_bounds__(256) void k_fine(const ull* __restrict__ ebuf,
                                              const int* __restrict__ gcursor,
                                              const int* __restrict__ bktbase,
                                              int* __restrict__ rowptr,
                                              float* __restrict__ dinv,
                                              int* __restrict__ csrc,
                                              int NN, int nbkt) {
  __shared__ int degl[BK_SIZE];
  __shared__ int lpl[BK_SIZE];
  __shared__ int ssum[256];
  int g = blockIdx.x;
  int tid = threadIdx.x;
  int cnt = gcursor[g];
  int base = bktbase[g];
  size_t ebase = (size_t)g * CAP;
  for (int j = tid; j < BK_SIZE; j += 256) degl[j] = 0;
  __syncthreads();
  for (int i = tid; i < cnt; i += 256)
    atomicAdd(&degl[(int)(ebuf[ebase + i] >> 32)], 1);
  __syncthreads();
  int d0 = degl[2 * tid], d1 = degl[2 * tid + 1];
  int s = d0 + d1;
  ssum[tid] = s;
  __syncthreads();
  for (int off = 1; off < 256; off <<= 1) {
    int a = (tid >= off) ? ssum[tid - off] : 0;
    __syncthreads();
    ssum[tid] += a;
    __syncthreads();
  }
  int excl = ssum[tid] - s;
  lpl[2 * tid] = excl;
  lpl[2 * tid + 1] = excl + d0;
  int node0 = g * BK_SIZE;
  int n0 = node0 + 2 * tid, n1 = n0 + 1;
  if (n0 < NN) {
    rowptr[n0] = base + excl;
    dinv[n0] = (d0 > 0) ? rsqrtf((float)d0) : 0.f;
  }
  if (n1 < NN) {
    rowptr[n1] = base + excl + d0;
    dinv[n1] = (d1 > 0) ? rsqrtf((float)d1) : 0.f;
  }
  if (g == nbkt - 1 && tid == 255) rowptr[NN] = base + excl + d0 + d1;
  __syncthreads();
  for (int i = tid; i < cnt; i += 256) {
    ull e = ebuf[ebase + i];
    int dl = (int)(e >> 32);
    int r = atomicAdd(&lpl[dl], 1);
    csrc[base + r] = (int)(uint)e;
  }
}

// 16-lane sub-group per node; fp8 rows (4B/lane = 4 elems), f32 accumulate
__global__ __launch_bounds__(256) void k_gather(const uint* __restrict__ x,
                                                const int* __restrict__ rowptr,
                                                const int* __restrict__ csrc,
                                                const float* __restrict__ dinv,
                                                uint* __restrict__ out, int NN) {
  int gid = blockIdx.x * blockDim.x + threadIdx.x;
  int node = gid >> 4;
  if (node >= NN) return;
  int sl = gid & 15;
  int beg = rowptr[node], end = rowptr[node + 1];
  float dn = dinv[node];
  float a0 = 0.f, a1 = 0.f, a2 = 0.f, a3 = 0.f;
  int i = beg;
  for (; i + 3 < end; i += 4) {
    int s0 = csrc[i], s1 = csrc[i + 1], s2 = csrc[i + 2], s3 = csrc[i + 3];
    float n0 = dinv[s0], n1 = dinv[s1], n2 = dinv[s2], n3 = dinv[s3];
    uint r0 = x[(size_t)s0 * 16 + sl];
    uint r1 = x[(size_t)s1 * 16 + sl];
    uint r2 = x[(size_t)s2 * 16 + sl];
    uint r3 = x[(size_t)s3 * 16 + sl];
    float4 d0 = dec4(r0), d1 = dec4(r1), d2 = dec4(r2), d3 = dec4(r3);
    a0 += n0 * d0.x; a1 += n0 * d0.y; a2 += n0 * d0.z; a3 += n0 * d0.w;
    a0 += n1 * d1.x; a1 += n1 * d1.y; a2 += n1 * d1.z; a3 += n1 * d1.w;
    a0 += n2 * d2.x; a1 += n2 * d2.y; a2 += n2 * d2.z; a3 += n2 * d2.w;
    a0 += n3 * d3.x; a1 += n3 * d3.y; a2 += n3 * d3.z; a3 += n3 * d3.w;
  }
  for (; i < end; ++i) {
    int s0 = csrc[i];
    float n0 = dinv[s0];
    float4 d0 = dec4(x[(size_t)s0 * 16 + sl]);
    a0 += n0 * d0.x; a1 += n0 * d0.y; a2 += n0 * d0.z; a3 += n0 * d0.w;
  }
  out[(size_t)node * 16 + sl] = enc4f(a0 * dn, a1 * dn, a2 * dn, a3 * dn);
}

// ---------------------------------------------------------------------------
// k_node (MFMA bf16): per 64-node tile; b1q/b2q decoded from fp8; E f32.
// ---------------------------------------------------------------------------
__device__ inline float fast_tanh(float x) {
  float t = __expf(fminf(fmaxf(2.f * x, -30.f), 30.f));
  return (t - 1.f) / (t + 1.f);
}

__device__ inline short8v cvt8(const float* p) {
  float4 f0 = *(const float4*)p;
  float4 f1 = *(const float4*)(p + 4);
  uint4 u;
  u.x = pack2(f0.x, f0.y); u.y = pack2(f0.z, f0.w);
  u.z = pack2(f1.x, f1.y); u.w = pack2(f1.z, f1.w);
  return *(short8v*)&u;
}

#define MFMA(a, b, c) __builtin_amdgcn_mfma_f32_16x16x32_bf16((a), (b), (c), 0, 0, 0)

__global__ __launch_bounds__(256, 2) void k_node(const float* __restrict__ E,
                                                 const float* __restrict__ E2,
                                                 const ushort* __restrict__ Wmh,
                                                 const float* __restrict__ bm,
                                                 const ushort* __restrict__ AWh,
                                                 const float* __restrict__ ab,
                                                 const float* __restrict__ qw,
                                                 const uint* __restrict__ b1q,
                                                 const uint* __restrict__ b2q,
                                                 float* __restrict__ Zf,
                                                 int NN) {
  __shared__ ushort Hl[64 * 72];   // H, then ZN (bf16, stride 72)
  __shared__ ushort Pl[64 * 72];   // ZP (bf16)
  int tid = threadIdx.x;
  int lane = tid & 63, wid = tid >> 6;
  int r15 = lane & 15, kg = lane >> 4;
  int node0 = blockIdx.x * 64;

  // ---- GEMM1: acc = E2 @ W0^T + b0 ----
  int arow = node0 + 16 * wid + r15;
  int arowc = min(arow, NN - 1);
  const float* e2p = E2 + (size_t)arowc * 64 + 8 * kg;
  short8v a0 = cvt8(e2p);
  short8v a1 = cvt8(e2p + 32);
  float4v acc[4];
#pragma unroll
  for (int b = 0; b < 4; ++b) {
    int col = r15 + 16 * b;
    short8v w0 = *(const short8v*)&Wmh[col * 64 + 8 * kg];
    short8v w1 = *(const short8v*)&Wmh[col * 64 + 32 + 8 * kg];
    float bias = bm[col];
    acc[b] = (float4v){bias, bias, bias, bias};
    acc[b] = MFMA(a0, w0, acc[b]);
    acc[b] = MFMA(a1, w1, acc[b]);
  }
#pragma unroll
  for (int b = 0; b < 4; ++b)
#pragma unroll
    for (int rr = 0; rr < 4; ++rr)
      Hl[(16 * wid + 4 * kg + rr) * 72 + 16 * b + r15] = f2b(fmaxf(acc[b][rr], 0.f));

  // stage ZP = (E + b1 + b2)/3 -> Pl (bf16); b1/b2 decoded from fp8
  {
    int row = tid >> 2;
    int c4 = (tid & 3) * 4;          // uint index (4 uints = 16 elems)
    int node = node0 + row;
    uint outp[8];
    if (node < NN) {
      const float* pe = E + (size_t)node * 64 + c4 * 4;
      uint4 q1 = *(const uint4*)(b1q + (size_t)node * 16 + c4);
      uint4 q2 = *(const uint4*)(b2q + (size_t)node * 16 + c4);
      float4 d1[4] = {dec4(q1.x), dec4(q1.y), dec4(q1.z), dec4(q1.w)};
      float4 d2[4] = {dec4(q2.x), dec4(q2.y), dec4(q2.z), dec4(q2.w)};
#pragma unroll
      for (int c = 0; c < 4; ++c) {
        float4 e4 = ((const float4*)pe)[c];
        float z0 = (e4.x + d1[c].x + d2[c].x) * (1.f / 3.f);
        float z1 = (e4.y + d1[c].y + d2[c].y) * (1.f / 3.f);
        float z2 = (e4.z + d1[c].z + d2[c].z) * (1.f / 3.f);
        float z3 = (e4.w + d1[c].w + d2[c].w) * (1.f / 3.f);
        outp[2 * c] = pack2(z0, z1);
        outp[2 * c + 1] = pack2(z2, z3);
      }
    } else {
#pragma unroll
      for (int c = 0; c < 8; ++c) outp[c] = 0;
    }
    int c0 = c4 * 4;
    *(uint4*)&Pl[row * 72 + c0] = *(uint4*)&outp[0];
    *(uint4*)&Pl[row * 72 + c0 + 8] = *(uint4*)&outp[4];
  }
  __syncthreads();

  // ---- GEMM2: acc2 = H @ W1^T + b1 ----
  const ushort* hap = &Hl[(16 * wid + r15) * 72 + 8 * kg];
  short8v ha0 = *(const short8v*)hap;
  short8v ha1 = *(const short8v*)(hap + 32);
  float4v acc2[4];
#pragma unroll
  for (int b = 0; b < 4; ++b) {
    int col = r15 + 16 * b;
    short8v w0 = *(const short8v*)&Wmh[4096 + col * 64 + 8 * kg];
    short8v w1 = *(const short8v*)&Wmh[4096 + col * 64 + 32 + 8 * kg];
    float bias = bm[64 + col];
    acc2[b] = (float4v){bias, bias, bias, bias};
    acc2[b] = MFMA(ha0, w0, acc2[b]);
    acc2[b] = MFMA(ha1, w1, acc2[b]);
  }
  __syncthreads();   // all Hl (H) reads done
#pragma unroll
  for (int b = 0; b < 4; ++b)
#pragma unroll
    for (int rr = 0; rr < 4; ++rr)
      Hl[(16 * wid + 4 * kg + rr) * 72 + 16 * b + r15] = f2b(fmaxf(acc2[b][rr], 0.f));
  __syncthreads();

  // ---- attention GEMMs ----
  const ushort* pap = &Pl[(16 * wid + r15) * 72 + 8 * kg];
  short8v pa0 = *(const short8v*)pap;
  short8v pa1 = *(const short8v*)(pap + 32);
  const ushort* nap = &Hl[(16 * wid + r15) * 72 + 8 * kg];
  short8v na0 = *(const short8v*)nap;
  short8v na1 = *(const short8v*)(nap + 32);
  float4v ac1[4], ac2[4];
#pragma unroll
  for (int b = 0; b < 4; ++b) {
    int col = r15 + 16 * b;
    short8v w0 = *(const short8v*)&AWh[col * 64 + 8 * kg];
    short8v w1 = *(const short8v*)&AWh[col * 64 + 32 + 8 * kg];
    float bias = ab[col];
    ac1[b] = (float4v){bias, bias, bias, bias};
    ac1[b] = MFMA(pa0, w0, ac1[b]);
    ac1[b] = MFMA(pa1, w1, ac1[b]);
    ac2[b] = (float4v){bias, bias, bias, bias};
    ac2[b] = MFMA(na0, w0, ac2[b]);
    ac2[b] = MFMA(na1, w1, ac2[b]);
  }

  // ---- epilogue: per-row softmax over {w_p, w_n}; Z -> Zf ----
  float qv[4];
#pragma unroll
  for (int b = 0; b < 4; ++b) qv[b] = qw[r15 + 16 * b];
#pragma unroll
  for (int rr = 0; rr < 4; ++rr) {
    float wp = 0.f, wn = 0.f;
#pragma unroll
    for (int b = 0; b < 4; ++b) {
      wp += fast_tanh(ac1[b][rr]) * qv[b];
      wn += fast_tanh(ac2[b][rr]) * qv[b];
    }
#pragma unroll
    for (int off = 8; off; off >>= 1) {
      wp += __shfl_xor(wp, off);
      wn += __shfl_xor(wn, off);
    }
    float m = fmaxf(wp, wn);
    float e1 = __expf(wp - m), e2 = __expf(wn - m);
    float inv = 1.f / (e1 + e2);
    float al0 = e1 * inv, al1 = e2 * inv;
    int row_l = 16 * wid + 4 * kg + rr;
    int node = node0 + row_l;
    if (node < NN) {
      float* op = Zf + (size_t)node * 64;
#pragma unroll
      for (int b = 0; b < 4; ++b) {
        int col = r15 + 16 * b;
        int li = row_l * 72 + col;
        op[col] = al0 * b2f(Pl[li]) + al1 * b2f(Hl[li]);
      }
    }
  }
}

// 16-lane sub-group per batch element; block handles 16; grid = ceil(B/16)
__global__ __launch_bounds__(256) void k_score(const float* __restrict__ Z,
                                               const int* __restrict__ u,
                                               const int* __restrict__ v,
                                               const int* __restrict__ n,
                                               const float* __restrict__ w,
                                               float* __restrict__ out, int B, int K) {
  __shared__ float xbuf[16][65];
  __shared__ float part[16];
  int t = threadIdx.x;
  int wv = t >> 6, lane = t & 63;
  int sg = lane >> 4, sl = lane & 15;
  int bloc = wv * 4 + sg;
  int b = blockIdx.x * 16 + bloc;
  float lossb = 0.f;
  if (b < B) {
    int uid = u[b], vid = v[b];
    float4 u4 = *(const float4*)&Z[(size_t)uid * 64 + sl * 4];
    float4 v4 = *(const float4*)&Z[(size_t)vid * 64 + sl * 4];
    float p = u4.x * v4.x + u4.y * v4.y + u4.z * v4.z + u4.w * v4.w;
#pragma unroll
    for (int off = 8; off; off >>= 1) p += __shfl_xor(p, off);
    float wb = w[b];
    float sgn = (wb > 0.f) ? 1.f : ((wb < 0.f) ? -1.f : 0.f);
    float sp = sgn * p;
    float regl = u4.x * u4.x + u4.y * u4.y + u4.z * u4.z + u4.w * u4.w
               + v4.x * v4.x + v4.y * v4.y + v4.z * v4.z + v4.w * v4.w;
    const int* nb_ = n + (size_t)b * K;
    for (int k = 0; k < K; ++k) {
      int nid = nb_[k];
      float4 n4 = *(const float4*)&Z[(size_t)nid * 64 + sl * 4];
      float d = u4.x * n4.x + u4.y * n4.y + u4.z * n4.z + u4.w * n4.w;
      regl += n4.x * n4.x + n4.y * n4.y + n4.z * n4.z + n4.w * n4.w;
#pragma unroll
      for (int off = 8; off; off >>= 1) d += __shfl_xor(d, off);
      if (sl == 0) xbuf[bloc][k] = sp - d;
    }
#pragma unroll
    for (int off = 8; off; off >>= 1) regl += __shfl_xor(regl, off);
    float sb = 0.f;
    for (int k = sl; k < K; k += 16) {
      float x = xbuf[bloc][k];
      sb += fminf(x, 0.f) - log1pf(expf(-fabsf(x)));
    }
#pragma unroll
    for (int off = 8; off; off >>= 1) sb += __shfl_xor(sb, off);
    lossb = -sb + 1e-4f * regl;
  }
  if (sl == 0) part[bloc] = (b < B) ? lossb : 0.f;
  __syncthreads();
  if (t == 0) {
    float s = 0.f;
#pragma unroll
    for (int i = 0; i < 16; ++i) s += part[i];
    unsafeAtomicAdd(out, s);
  }
}

extern "C" void kernel_launch(void* const* d_in, const int* in_sizes, int n_in,
                              void* d_out, int out_size, void* d_ws, size_t ws_size,
                              hipStream_t stream) {
  const float* E  = (const float*)d_in[0];
  const float* E2 = (const float*)d_in[1];
  const float* Wm = (const float*)d_in[2];
  const float* bm = (const float*)d_in[3];
  const float* AW = (const float*)d_in[4];
  const float* ab = (const float*)d_in[5];
  const float* qw = (const float*)d_in[6];
  const int*   ei = (const int*)d_in[7];
  const int*   u  = (const int*)d_in[8];
  const int*   v  = (const int*)d_in[9];
  const int*   nn = (const int*)d_in[10];
  const float* w  = (const float*)d_in[11];

  const int NN = in_sizes[0] / 64;        // 150000
  const int NE = in_sizes[7] / 2;         // 3200000
  const int B  = in_sizes[8];             // 16384
  const int K  = in_sizes[10] / B;        // 40
  const int NBKT = (NN + BK_SIZE - 1) / BK_SIZE;   // 293

  const int* src = ei;
  const int* dst = ei + NE;

  // workspace layout
  float*  ws      = (float*)d_ws;
  float*  dinv    = ws;                               // NN floats
  uint*   E8      = (uint*)(dinv + NN);               // NN*16 uints (fp8 rows)
  uint*   b1q     = E8 + (size_t)NN * 16;
  uint*   b2q     = b1q + (size_t)NN * 16;
  ushort* Wmh     = (ushort*)(b2q + (size_t)NN * 16); // 8192 ushorts
  ushort* AWh     = Wmh + 8192;                       // 4096 ushorts
  int*    rowptr  = (int*)(AWh + 4096);               // NN+1 ints
  int*    csrc    = rowptr + NN + 1;                  // NE ints
  int*    gcursor = csrc + NE;                        // NBKT ints
  int*    bktbase = gcursor + NBKT;                   // NBKT+1 ints
  ull*    ebuf    = (ull*)(((uintptr_t)(bktbase + NBKT + 1) + 15) & ~(uintptr_t)15);
  float*  Zf      = (float*)ebuf;                     // aliases ebuf (dead after k_fine)
  float*  outf    = (float*)d_out;

  hipMemsetAsync(gcursor, 0, (size_t)NBKT * sizeof(int), stream);
  hipMemsetAsync(outf, 0, sizeof(float), stream);

  k_tofp8<<<(NN * 4 + 255) / 256, 256, 0, stream>>>(E, E8, NN * 4);
  k_half<<<4, 256, 0, stream>>>(Wm, Wmh, 1024);
  k_half<<<2, 256, 0, stream>>>(AW, AWh, 512);

  int chunk = (NE + 255) / 256;
  k_bucket<<<256, 256, 0, stream>>>(src, dst, gcursor, ebuf, NE, NBKT, chunk);
  k_small<<<1, 1024, 0, stream>>>(gcursor, bktbase, NBKT);
  k_fine<<<NBKT, 256, 0, stream>>>(ebuf, gcursor, bktbase, rowptr, dinv, csrc, NN, NBKT);

  int gatherBlocks = ((size_t)NN * 16 + 255) / 256;   // 16 lanes per node
  k_gather<<<gatherBlocks, 256, 0, stream>>>(E8, rowptr, csrc, dinv, b1q, NN);
  k_gather<<<gatherBlocks, 256, 0, stream>>>(b1q, rowptr, csrc, dinv, b2q, NN);

  int nodeTiles = (NN + 63) / 64;
  k_node<<<nodeTiles, 256, 0, stream>>>(E, E2, Wmh, bm, AWh, ab, qw, b1q, b2q, Zf, NN);

  k_score<<<(B + 15) / 16, 256, 0, stream>>>(Zf, u, v, nn, w, outf, B, K);
}

// Round 16
// 294.054 us; speedup vs baseline: 2.6143x; 1.0613x over previous
//
#include <hip/hip_runtime.h>
#include <math.h>

// ---------------------------------------------------------------------------
// SiReN loss on MI355X — round 16: k_bucket parallelism fix.
// 256x256 -> 512x512 (16 waves/CU candidate): latency-bound at 9.6% occupancy,
// VALUBusy 2%. Reservation atomics 75K -> 150K (~7us) — net win.
// ---------------------------------------------------------------------------

typedef unsigned int uint;
typedef unsigned short ushort;
typedef unsigned char uchar;
typedef unsigned long long ull;
typedef __attribute__((ext_vector_type(8))) short short8v;
typedef __attribute__((ext_vector_type(4))) float float4v;
typedef __attribute__((ext_vector_type(2))) float float2v;

#define BK_SHIFT 9
#define BK_SIZE 512
#define CAP 20480

#if __has_builtin(__builtin_amdgcn_cvt_pk_f32_fp8) && __has_builtin(__builtin_amdgcn_cvt_pk_fp8_f32)
#define HW_FP8 1
#else
#define HW_FP8 0
#endif

__device__ inline float b2f(ushort u) { return __uint_as_float(((uint)u) << 16); }
__device__ inline ushort f2b(float f) {
  uint u = __float_as_uint(f);
  return (ushort)((u + 0x7fffu + ((u >> 16) & 1u)) >> 16);
}
__device__ inline uint pack2(float lo, float hi) {
  return (uint)f2b(lo) | ((uint)f2b(hi) << 16);
}

// ---- fp8 e4m3 helpers ----
__device__ inline float dec1(uint u) {
  uint e = (u >> 3) & 0xFu;
  uint m = u & 7u;
  uint s = (u & 0x80u) << 24;
  float norm = __uint_as_float(s | ((e + 120u) << 23) | (m << 20));
  float den = __uint_as_float(s | 0x3F800000u) * (float)(int)m * 0.001953125f;
  return e ? norm : den;
}
__device__ inline uint enc1(float x) {
  uint s = (__float_as_uint(x) >> 24) & 0x80u;
  float ax = fminf(fabsf(x), 448.f);
  uint r;
  if (ax < 0.015625f) {
    r = (uint)(int)rintf(ax * 512.f);
  } else {
    uint b = __float_as_uint(ax);
    b += 0x7FFFFu + ((b >> 20) & 1u);
    uint e = (b >> 23) - 120u;
    r = (e > 15u) ? 0x7Eu : ((e << 3) | ((b >> 20) & 7u));
  }
  return s | r;
}
__device__ inline float4 dec4(uint v) {
#if HW_FP8
  float2v lo = __builtin_amdgcn_cvt_pk_f32_fp8((int)v, false);
  float2v hi = __builtin_amdgcn_cvt_pk_f32_fp8((int)v, true);
  return make_float4(lo[0], lo[1], hi[0], hi[1]);
#else
  return make_float4(dec1(v & 0xFFu), dec1((v >> 8) & 0xFFu),
                     dec1((v >> 16) & 0xFFu), dec1(v >> 24));
#endif
}
__device__ inline uint enc4f(float a, float b, float c, float d) {
#if HW_FP8
  int v = 0;
  v = __builtin_amdgcn_cvt_pk_fp8_f32(a, b, v, false);
  v = __builtin_amdgcn_cvt_pk_fp8_f32(c, d, v, true);
  return (uint)v;
#else
  return enc1(a) | (enc1(b) << 8) | (enc1(c) << 16) | (enc1(d) << 24);
#endif
}

// f32 -> bf16 converter: thread handles 8 elems (weights)
__global__ void k_half(const float* __restrict__ x, ushort* __restrict__ out, int n8) {
  int i = blockIdx.x * blockDim.x + threadIdx.x;
  if (i >= n8) return;
  const float4* p = (const float4*)(x + (size_t)i * 8);
  float4 a = p[0], b = p[1];
  uint4 o;
  o.x = pack2(a.x, a.y); o.y = pack2(a.z, a.w);
  o.z = pack2(b.x, b.y); o.w = pack2(b.z, b.w);
  ((uint4*)out)[i] = o;
}

// f32 -> fp8 converter: thread handles 16 elems
__global__ void k_tofp8(const float* __restrict__ x, uint* __restrict__ out, int n16) {
  int i = blockIdx.x * blockDim.x + threadIdx.x;
  if (i >= n16) return;
  const float4* p = (const float4*)(x + (size_t)i * 16);
  float4 f0 = p[0], f1 = p[1], f2 = p[2], f3 = p[3];
  uint4 o;
  o.x = enc4f(f0.x, f0.y, f0.z, f0.w);
  o.y = enc4f(f1.x, f1.y, f1.z, f1.w);
  o.z = enc4f(f2.x, f2.y, f2.z, f2.w);
  o.w = enc4f(f3.x, f3.y, f3.z, f3.w);
  ((uint4*)out)[i] = o;
}

// bucket-partition edges: LDS histogram + one global atomic per (block,bucket)
__global__ __launch_bounds__(512) void k_bucket(const int* __restrict__ src,
                                                const int* __restrict__ dst,
                                                int* __restrict__ gcursor,
                                                ull* __restrict__ ebuf,
                                                int NE, int nbkt, int chunk) {
  __shared__ int hist[1024];
  __shared__ int curb[1024];
  int tid = threadIdx.x;
  int nt = blockDim.x;
  for (int g = tid; g < nbkt; g += nt) hist[g] = 0;
  __syncthreads();
  int lo = blockIdx.x * chunk;
  int hi = min(lo + chunk, NE);
  for (int e = lo + tid; e < hi; e += nt)
    atomicAdd(&hist[dst[e] >> BK_SHIFT], 1);
  __syncthreads();
  for (int g = tid; g < nbkt; g += nt) {
    int c = hist[g];
    curb[g] = (c > 0) ? atomicAdd(&gcursor[g], c) : 0;
  }
  __syncthreads();
  for (int e = lo + tid; e < hi; e += nt) {
    int d = dst[e];
    int g = d >> BK_SHIFT;
    int pos = atomicAdd(&curb[g], 1);
    if (pos < CAP)
      ebuf[(size_t)g * CAP + pos] = ((ull)(uint)(d & (BK_SIZE - 1)) << 32) | (uint)src[e];
  }
}

// exclusive scan of bucket totals (nbkt <= 1024), single block
__global__ void k_small(const int* __restrict__ gcursor, int* __restrict__ bktbase,
                        int nbkt) {
  __shared__ int sm[1024];
  int t = threadIdx.x;
  int v = (t < nbkt) ? gcursor[t] : 0;
  sm[t] = v;
  __syncthreads();
  for (int off = 1; off < 1024; off <<= 1) {
    int a = (t >= off) ? sm[t - off] : 0;
    __syncthreads();
    sm[t] += a;
    __syncthreads();
  }
  if (t < nbkt) bktbase[t] = sm[t] - v;
  if (t == 0) bktbase[nbkt] = sm[1023];
}

// per-bucket: LDS count -> LDS scan -> rowptr+dinv, then place csrc
__global__ __launch_bounds__(256) void k_fine(const ull* __restrict__ ebuf,
                                              const int* __restrict__ gcursor,
                                              const int* __restrict__ bktbase,
                                              int* __restrict__ rowptr,
                                              float* __restrict__ dinv,
                                              int* __restrict__ csrc,
                                              int NN, int nbkt) {
  __shared__ int degl[BK_SIZE];
  __shared__ int lpl[BK_SIZE];
  __shared__ int ssum[256];
  int g = blockIdx.x;
  int tid = threadIdx.x;
  int cnt = gcursor[g];
  int base = bktbase[g];
  size_t ebase = (size_t)g * CAP;
  for (int j = tid; j < BK_SIZE; j += 256) degl[j] = 0;
  __syncthreads();
  for (int i = tid; i < cnt; i += 256)
    atomicAdd(&degl[(int)(ebuf[ebase + i] >> 32)], 1);
  __syncthreads();
  int d0 = degl[2 * tid], d1 = degl[2 * tid + 1];
  int s = d0 + d1;
  ssum[tid] = s;
  __syncthreads();
  for (int off = 1; off < 256; off <<= 1) {
    int a = (tid >= off) ? ssum[tid - off] : 0;
    __syncthreads();
    ssum[tid] += a;
    __syncthreads();
  }
  int excl = ssum[tid] - s;
  lpl[2 * tid] = excl;
  lpl[2 * tid + 1] = excl + d0;
  int node0 = g * BK_SIZE;
  int n0 = node0 + 2 * tid, n1 = n0 + 1;
  if (n0 < NN) {
    rowptr[n0] = base + excl;
    dinv[n0] = (d0 > 0) ? rsqrtf((float)d0) : 0.f;
  }
  if (n1 < NN) {
    rowptr[n1] = base + excl + d0;
    dinv[n1] = (d1 > 0) ? rsqrtf((float)d1) : 0.f;
  }
  if (g == nbkt - 1 && tid == 255) rowptr[NN] = base + excl + d0 + d1;
  __syncthreads();
  for (int i = tid; i < cnt; i += 256) {
    ull e = ebuf[ebase + i];
    int dl = (int)(e >> 32);
    int r = atomicAdd(&lpl[dl], 1);
    csrc[base + r] = (int)(uint)e;
  }
}

// 16-lane sub-group per node; fp8 rows (4B/lane = 4 elems), f32 accumulate
__global__ __launch_bounds__(256) void k_gather(const uint* __restrict__ x,
                                                const int* __restrict__ rowptr,
                                                const int* __restrict__ csrc,
                                                const float* __restrict__ dinv,
                                                uint* __restrict__ out, int NN) {
  int gid = blockIdx.x * blockDim.x + threadIdx.x;
  int node = gid >> 4;
  if (node >= NN) return;
  int sl = gid & 15;
  int beg = rowptr[node], end = rowptr[node + 1];
  float dn = dinv[node];
  float a0 = 0.f, a1 = 0.f, a2 = 0.f, a3 = 0.f;
  int i = beg;
  for (; i + 3 < end; i += 4) {
    int s0 = csrc[i], s1 = csrc[i + 1], s2 = csrc[i + 2], s3 = csrc[i + 3];
    float n0 = dinv[s0], n1 = dinv[s1], n2 = dinv[s2], n3 = dinv[s3];
    uint r0 = x[(size_t)s0 * 16 + sl];
    uint r1 = x[(size_t)s1 * 16 + sl];
    uint r2 = x[(size_t)s2 * 16 + sl];
    uint r3 = x[(size_t)s3 * 16 + sl];
    float4 d0 = dec4(r0), d1 = dec4(r1), d2 = dec4(r2), d3 = dec4(r3);
    a0 += n0 * d0.x; a1 += n0 * d0.y; a2 += n0 * d0.z; a3 += n0 * d0.w;
    a0 += n1 * d1.x; a1 += n1 * d1.y; a2 += n1 * d1.z; a3 += n1 * d1.w;
    a0 += n2 * d2.x; a1 += n2 * d2.y; a2 += n2 * d2.z; a3 += n2 * d2.w;
    a0 += n3 * d3.x; a1 += n3 * d3.y; a2 += n3 * d3.z; a3 += n3 * d3.w;
  }
  for (; i < end; ++i) {
    int s0 = csrc[i];
    float n0 = dinv[s0];
    float4 d0 = dec4(x[(size_t)s0 * 16 + sl]);
    a0 += n0 * d0.x; a1 += n0 * d0.y; a2 += n0 * d0.z; a3 += n0 * d0.w;
  }
  out[(size_t)node * 16 + sl] = enc4f(a0 * dn, a1 * dn, a2 * dn, a3 * dn);
}

// ---------------------------------------------------------------------------
// k_node (MFMA bf16): per 64-node tile; b1q/b2q decoded from fp8; E f32.
// ---------------------------------------------------------------------------
__device__ inline float fast_tanh(float x) {
  float t = __expf(fminf(fmaxf(2.f * x, -30.f), 30.f));
  return (t - 1.f) / (t + 1.f);
}

__device__ inline short8v cvt8(const float* p) {
  float4 f0 = *(const float4*)p;
  float4 f1 = *(const float4*)(p + 4);
  uint4 u;
  u.x = pack2(f0.x, f0.y); u.y = pack2(f0.z, f0.w);
  u.z = pack2(f1.x, f1.y); u.w = pack2(f1.z, f1.w);
  return *(short8v*)&u;
}

#define MFMA(a, b, c) __builtin_amdgcn_mfma_f32_16x16x32_bf16((a), (b), (c), 0, 0, 0)

__global__ __launch_bounds__(256, 2) void k_node(const float* __restrict__ E,
                                                 const float* __restrict__ E2,
                                                 const ushort* __restrict__ Wmh,
                                                 const float* __restrict__ bm,
                                                 const ushort* __restrict__ AWh,
                                                 const float* __restrict__ ab,
                                                 const float* __restrict__ qw,
                                                 const uint* __restrict__ b1q,
                                                 const uint* __restrict__ b2q,
                                                 float* __restrict__ Zf,
                                                 int NN) {
  __shared__ ushort Hl[64 * 72];
  __shared__ ushort Pl[64 * 72];
  int tid = threadIdx.x;
  int lane = tid & 63, wid = tid >> 6;
  int r15 = lane & 15, kg = lane >> 4;
  int node0 = blockIdx.x * 64;

  // ---- GEMM1: acc = E2 @ W0^T + b0 ----
  int arow = node0 + 16 * wid + r15;
  int arowc = min(arow, NN - 1);
  const float* e2p = E2 + (size_t)arowc * 64 + 8 * kg;
  short8v a0 = cvt8(e2p);
  short8v a1 = cvt8(e2p + 32);
  float4v acc[4];
#pragma unroll
  for (int b = 0; b < 4; ++b) {
    int col = r15 + 16 * b;
    short8v w0 = *(const short8v*)&Wmh[col * 64 + 8 * kg];
    short8v w1 = *(const short8v*)&Wmh[col * 64 + 32 + 8 * kg];
    float bias = bm[col];
    acc[b] = (float4v){bias, bias, bias, bias};
    acc[b] = MFMA(a0, w0, acc[b]);
    acc[b] = MFMA(a1, w1, acc[b]);
  }
#pragma unroll
  for (int b = 0; b < 4; ++b)
#pragma unroll
    for (int rr = 0; rr < 4; ++rr)
      Hl[(16 * wid + 4 * kg + rr) * 72 + 16 * b + r15] = f2b(fmaxf(acc[b][rr], 0.f));

  // stage ZP = (E + b1 + b2)/3 -> Pl (bf16); b1/b2 decoded from fp8
  {
    int row = tid >> 2;
    int c4 = (tid & 3) * 4;
    int node = node0 + row;
    uint outp[8];
    if (node < NN) {
      const float* pe = E + (size_t)node * 64 + c4 * 4;
      uint4 q1 = *(const uint4*)(b1q + (size_t)node * 16 + c4);
      uint4 q2 = *(const uint4*)(b2q + (size_t)node * 16 + c4);
      float4 d1[4] = {dec4(q1.x), dec4(q1.y), dec4(q1.z), dec4(q1.w)};
      float4 d2[4] = {dec4(q2.x), dec4(q2.y), dec4(q2.z), dec4(q2.w)};
#pragma unroll
      for (int c = 0; c < 4; ++c) {
        float4 e4 = ((const float4*)pe)[c];
        float z0 = (e4.x + d1[c].x + d2[c].x) * (1.f / 3.f);
        float z1 = (e4.y + d1[c].y + d2[c].y) * (1.f / 3.f);
        float z2 = (e4.z + d1[c].z + d2[c].z) * (1.f / 3.f);
        float z3 = (e4.w + d1[c].w + d2[c].w) * (1.f / 3.f);
        outp[2 * c] = pack2(z0, z1);
        outp[2 * c + 1] = pack2(z2, z3);
      }
    } else {
#pragma unroll
      for (int c = 0; c < 8; ++c) outp[c] = 0;
    }
    int c0 = c4 * 4;
    *(uint4*)&Pl[row * 72 + c0] = *(uint4*)&outp[0];
    *(uint4*)&Pl[row * 72 + c0 + 8] = *(uint4*)&outp[4];
  }
  __syncthreads();

  // ---- GEMM2: acc2 = H @ W1^T + b1 ----
  const ushort* hap = &Hl[(16 * wid + r15) * 72 + 8 * kg];
  short8v ha0 = *(const short8v*)hap;
  short8v ha1 = *(const short8v*)(hap + 32);
  float4v acc2[4];
#pragma unroll
  for (int b = 0; b < 4; ++b) {
    int col = r15 + 16 * b;
    short8v w0 = *(const short8v*)&Wmh[4096 + col * 64 + 8 * kg];
    short8v w1 = *(const short8v*)&Wmh[4096 + col * 64 + 32 + 8 * kg];
    float bias = bm[64 + col];
    acc2[b] = (float4v){bias, bias, bias, bias};
    acc2[b] = MFMA(ha0, w0, acc2[b]);
    acc2[b] = MFMA(ha1, w1, acc2[b]);
  }
  __syncthreads();
#pragma unroll
  for (int b = 0; b < 4; ++b)
#pragma unroll
    for (int rr = 0; rr < 4; ++rr)
      Hl[(16 * wid + 4 * kg + rr) * 72 + 16 * b + r15] = f2b(fmaxf(acc2[b][rr], 0.f));
  __syncthreads();

  // ---- attention GEMMs ----
  const ushort* pap = &Pl[(16 * wid + r15) * 72 + 8 * kg];
  short8v pa0 = *(const short8v*)pap;
  short8v pa1 = *(const short8v*)(pap + 32);
  const ushort* nap = &Hl[(16 * wid + r15) * 72 + 8 * kg];
  short8v na0 = *(const short8v*)nap;
  short8v na1 = *(const short8v*)(nap + 32);
  float4v ac1[4], ac2[4];
#pragma unroll
  for (int b = 0; b < 4; ++b) {
    int col = r15 + 16 * b;
    short8v w0 = *(const short8v*)&AWh[col * 64 + 8 * kg];
    short8v w1 = *(const short8v*)&AWh[col * 64 + 32 + 8 * kg];
    float bias = ab[col];
    ac1[b] = (float4v){bias, bias, bias, bias};
    ac1[b] = MFMA(pa0, w0, ac1[b]);
    ac1[b] = MFMA(pa1, w1, ac1[b]);
    ac2[b] = (float4v){bias, bias, bias, bias};
    ac2[b] = MFMA(na0, w0, ac2[b]);
    ac2[b] = MFMA(na1, w1, ac2[b]);
  }

  // ---- epilogue: per-row softmax over {w_p, w_n}; Z -> Zf ----
  float qv[4];
#pragma unroll
  for (int b = 0; b < 4; ++b) qv[b] = qw[r15 + 16 * b];
#pragma unroll
  for (int rr = 0; rr < 4; ++rr) {
    float wp = 0.f, wn = 0.f;
#pragma unroll
    for (int b = 0; b < 4; ++b) {
      wp += fast_tanh(ac1[b][rr]) * qv[b];
      wn += fast_tanh(ac2[b][rr]) * qv[b];
    }
#pragma unroll
    for (int off = 8; off; off >>= 1) {
      wp += __shfl_xor(wp, off);
      wn += __shfl_xor(wn, off);
    }
    float m = fmaxf(wp, wn);
    float e1 = __expf(wp - m), e2 = __expf(wn - m);
    float inv = 1.f / (e1 + e2);
    float al0 = e1 * inv, al1 = e2 * inv;
    int row_l = 16 * wid + 4 * kg + rr;
    int node = node0 + row_l;
    if (node < NN) {
      float* op = Zf + (size_t)node * 64;
#pragma unroll
      for (int b = 0; b < 4; ++b) {
        int col = r15 + 16 * b;
        int li = row_l * 72 + col;
        op[col] = al0 * b2f(Pl[li]) + al1 * b2f(Hl[li]);
      }
    }
  }
}

// 16-lane sub-group per batch element; block handles 16; grid = ceil(B/16)
__global__ __launch_bounds__(256) void k_score(const float* __restrict__ Z,
                                               const int* __restrict__ u,
                                               const int* __restrict__ v,
                                               const int* __restrict__ n,
                                               const float* __restrict__ w,
                                               float* __restrict__ out, int B, int K) {
  __shared__ float xbuf[16][65];
  __shared__ float part[16];
  int t = threadIdx.x;
  int wv = t >> 6, lane = t & 63;
  int sg = lane >> 4, sl = lane & 15;
  int bloc = wv * 4 + sg;
  int b = blockIdx.x * 16 + bloc;
  float lossb = 0.f;
  if (b < B) {
    int uid = u[b], vid = v[b];
    float4 u4 = *(const float4*)&Z[(size_t)uid * 64 + sl * 4];
    float4 v4 = *(const float4*)&Z[(size_t)vid * 64 + sl * 4];
    float p = u4.x * v4.x + u4.y * v4.y + u4.z * v4.z + u4.w * v4.w;
#pragma unroll
    for (int off = 8; off; off >>= 1) p += __shfl_xor(p, off);
    float wb = w[b];
    float sgn = (wb > 0.f) ? 1.f : ((wb < 0.f) ? -1.f : 0.f);
    float sp = sgn * p;
    float regl = u4.x * u4.x + u4.y * u4.y + u4.z * u4.z + u4.w * u4.w
               + v4.x * v4.x + v4.y * v4.y + v4.z * v4.z + v4.w * v4.w;
    const int* nb_ = n + (size_t)b * K;
    for (int k = 0; k < K; ++k) {
      int nid = nb_[k];
      float4 n4 = *(const float4*)&Z[(size_t)nid * 64 + sl * 4];
      float d = u4.x * n4.x + u4.y * n4.y + u4.z * n4.z + u4.w * n4.w;
      regl += n4.x * n4.x + n4.y * n4.y + n4.z * n4.z + n4.w * n4.w;
#pragma unroll
      for (int off = 8; off; off >>= 1) d += __shfl_xor(d, off);
      if (sl == 0) xbuf[bloc][k] = sp - d;
    }
#pragma unroll
    for (int off = 8; off; off >>= 1) regl += __shfl_xor(regl, off);
    float sb = 0.f;
    for (int k = sl; k < K; k += 16) {
      float x = xbuf[bloc][k];
      sb += fminf(x, 0.f) - log1pf(expf(-fabsf(x)));
    }
#pragma unroll
    for (int off = 8; off; off >>= 1) sb += __shfl_xor(sb, off);
    lossb = -sb + 1e-4f * regl;
  }
  if (sl == 0) part[bloc] = (b < B) ? lossb : 0.f;
  __syncthreads();
  if (t == 0) {
    float s = 0.f;
#pragma unroll
    for (int i = 0; i < 16; ++i) s += part[i];
    unsafeAtomicAdd(out, s);
  }
}

extern "C" void kernel_launch(void* const* d_in, const int* in_sizes, int n_in,
                              void* d_out, int out_size, void* d_ws, size_t ws_size,
                              hipStream_t stream) {
  const float* E  = (const float*)d_in[0];
  const float* E2 = (const float*)d_in[1];
  const float* Wm = (const float*)d_in[2];
  const float* bm = (const float*)d_in[3];
  const float* AW = (const float*)d_in[4];
  const float* ab = (const float*)d_in[5];
  const float* qw = (const float*)d_in[6];
  const int*   ei = (const int*)d_in[7];
  const int*   u  = (const int*)d_in[8];
  const int*   v  = (const int*)d_in[9];
  const int*   nn = (const int*)d_in[10];
  const float* w  = (const float*)d_in[11];

  const int NN = in_sizes[0] / 64;        // 150000
  const int NE = in_sizes[7] / 2;         // 3200000
  const int B  = in_sizes[8];             // 16384
  const int K  = in_sizes[10] / B;        // 40
  const int NBKT = (NN + BK_SIZE - 1) / BK_SIZE;   // 293

  const int* src = ei;
  const int* dst = ei + NE;

  // workspace layout
  float*  ws      = (float*)d_ws;
  float*  dinv    = ws;                               // NN floats
  uint*   E8      = (uint*)(dinv + NN);               // NN*16 uints (fp8 rows)
  uint*   b1q     = E8 + (size_t)NN * 16;
  uint*   b2q     = b1q + (size_t)NN * 16;
  ushort* Wmh     = (ushort*)(b2q + (size_t)NN * 16); // 8192 ushorts
  ushort* AWh     = Wmh + 8192;                       // 4096 ushorts
  int*    rowptr  = (int*)(AWh + 4096);               // NN+1 ints
  int*    csrc    = rowptr + NN + 1;                  // NE ints
  int*    gcursor = csrc + NE;                        // NBKT ints
  int*    bktbase = gcursor + NBKT;                   // NBKT+1 ints
  ull*    ebuf    = (ull*)(((uintptr_t)(bktbase + NBKT + 1) + 15) & ~(uintptr_t)15);
  float*  Zf      = (float*)ebuf;                     // aliases ebuf (dead after k_fine)
  float*  outf    = (float*)d_out;

  hipMemsetAsync(gcursor, 0, (size_t)NBKT * sizeof(int), stream);
  hipMemsetAsync(outf, 0, sizeof(float), stream);

  k_tofp8<<<(NN * 4 + 255) / 256, 256, 0, stream>>>(E, E8, NN * 4);
  k_half<<<4, 256, 0, stream>>>(Wm, Wmh, 1024);
  k_half<<<2, 256, 0, stream>>>(AW, AWh, 512);

  const int BUCKET_BLOCKS = 512;
  int chunk = (NE + BUCKET_BLOCKS - 1) / BUCKET_BLOCKS;
  k_bucket<<<BUCKET_BLOCKS, 512, 0, stream>>>(src, dst, gcursor, ebuf, NE, NBKT, chunk);
  k_small<<<1, 1024, 0, stream>>>(gcursor, bktbase, NBKT);
  k_fine<<<NBKT, 256, 0, stream>>>(ebuf, gcursor, bktbase, rowptr, dinv, csrc, NN, NBKT);

  int gatherBlocks = ((size_t)NN * 16 + 255) / 256;   // 16 lanes per node
  k_gather<<<gatherBlocks, 256, 0, stream>>>(E8, rowptr, csrc, dinv, b1q, NN);
  k_gather<<<gatherBlocks, 256, 0, stream>>>(b1q, rowptr, csrc, dinv, b2q, NN);

  int nodeTiles = (NN + 63) / 64;
  k_node<<<nodeTiles, 256, 0, stream>>>(E, E2, Wmh, bm, AWh, ab, qw, b1q, b2q, Zf, NN);

  k_score<<<(B + 15) / 16, 256, 0, stream>>>(Zf, u, v, nn, w, outf, B, K);
}